// Round 16
// baseline (183.611 us; speedup 1.0000x reference)
//
#include <hip/hip_runtime.h>
#include <cstddef>

#define TPB 256

typedef short bf8v   __attribute__((ext_vector_type(8)));   // 8 bf16 bit-patterns
typedef float f32x4  __attribute__((ext_vector_type(4)));
typedef float f32x16 __attribute__((ext_vector_type(16)));
typedef unsigned short u16;

#define PSZ 2048     // u16 per LDS plane [64][32] (rgemm staging)
#define PSZ2 4096    // u16 per LDS plane [64][64] (BK=64 staging)
#define LSTR 40      // legacy stride for sgemm16 staging
#define BUF1 2560
#define CSTR 68      // f32 LDS epilogue-tile row stride

static __device__ __forceinline__ u16 f2bf(float x) {
  unsigned int u = __float_as_uint(x);
  u = (u + 0x7FFFu + ((u >> 16) & 1u)) >> 16;   // RNE f32 -> bf16
  return (u16)u;
}
static __device__ __forceinline__ float bf2f(u16 x) {
  return __uint_as_float(((unsigned int)x) << 16);
}
static __device__ __forceinline__ float sigmoidf_(float x) {
  return 1.0f / (1.0f + __expf(-x));            // fast exp (v_exp_f32)
}
static __device__ __forceinline__ float spf_(float v) {   // fast softplus
  return (v > 15.0f) ? v : __logf(1.0f + __expf(v));
}
static __device__ __forceinline__ bf8v neg8(bf8v a) {
  #pragma unroll
  for (int i = 0; i < 8; ++i) a[i] ^= (short)0x8000;
  return a;
}
static __device__ __forceinline__ void pack8(const float4& x, const float4& y,
                                             u16* dst) {
  unsigned int* d = (unsigned int*)dst;
  d[0] = ((unsigned)f2bf(x.y) << 16) | f2bf(x.x);
  d[1] = ((unsigned)f2bf(x.w) << 16) | f2bf(x.z);
  d[2] = ((unsigned)f2bf(y.y) << 16) | f2bf(y.x);
  d[3] = ((unsigned)f2bf(y.w) << 16) | f2bf(y.z);
}
static __device__ __forceinline__ uint2 packbf4(float a, float b, float c, float d) {
  uint2 r;
  r.x = ((unsigned)f2bf(b) << 16) | f2bf(a);
  r.y = ((unsigned)f2bf(d) << 16) | f2bf(c);
  return r;
}
// async global->LDS, 16B per lane; LDS dest is wave-uniform base + lane*16
static __device__ __forceinline__ void gload16(const u16* g, u16* l) {
  __builtin_amdgcn_global_load_lds((const __attribute__((address_space(1))) void*)g,
                                   (__attribute__((address_space(3))) void*)l,
                                   16, 0, 0);
}
// BK=32 fragment read with k-chunk XOR swizzle (rgemm path, 16x16x32)
static __device__ __forceinline__ bf8v fragld(const u16* plane, int r, int kq) {
  int kb = (kq << 4) ^ (((r >> 1) & 3) << 4);
  return *(const bf8v*)(plane + r * 32 + (kb >> 1));
}
// BK=64, 32x32x16 fragment read: row r (0..63), slice s (0..3), half kh (0..1)
static __device__ __forceinline__ bf8v fragld32(const u16* plane, int r, int s, int kh) {
  int ch = ((s << 1) + kh) ^ (r & 7);
  return *(const bf8v*)(plane + r * 64 + (ch << 3));
}
// XCD-aware bijective block swizzle (T % 8 == 0)
static __device__ __forceinline__ int swz8(int flat, int T) {
  return (flat & 7) * (T >> 3) + (flat >> 3);
}

#define WAITV(n) asm volatile("s_waitcnt vmcnt(" #n ")" ::: "memory")

// ---------------------------------------------------------------------------
// A = (v - v^T)re + i(v + v^T)im ; N = I - A   -> bf16 planes
// ---------------------------------------------------------------------------
__global__ __launch_bounds__(TPB) void build_a_k(
    const float* __restrict__ vre, const float* __restrict__ vim,
    u16* __restrict__ Ar, u16* __restrict__ Ai,
    u16* __restrict__ Nr, u16* __restrict__ Ni)
{
  int idx = blockIdx.x * TPB + threadIdx.x;
  int i = idx >> 10, j = idx & 1023;
  float ar = vre[idx] - vre[j * 1024 + i];
  float ai = vim[idx] + vim[j * 1024 + i];
  float dg = (i == j) ? 1.0f : 0.0f;
  Ar[idx] = f2bf(ar);       Ai[idx] = f2bf(ai);
  Nr[idx] = f2bf(dg - ar);  Ni[idx] = f2bf(-ai);
}

// ---------------------------------------------------------------------------
// complex-NT, BK=64, 2-buffer counted-vmcnt pipeline, 32x32x16 MFMA.
//   BNEG=0 (B-plane = A):     B_true = (-b^r, +b^i)
//   BNEG=1 (B-plane = A^2k):  B_true = (+b^r, -b^i)
// Each wave computes one 32x32 quadrant; acc = 2 x f32x16.
// ---------------------------------------------------------------------------
#define CG_PRELUDE                                                           \
  __shared__ __align__(16) u16 lds[2 * 4 * PSZ2];       /* 64KB */           \
  int tid = threadIdx.x;                                                     \
  int lane = tid & 63;                                                       \
  int wr = (tid >> 7) & 1, wc = (tid >> 6) & 1;                              \
  int lr8_ = ((tid & 63) >> 3) + ((tid >> 6) << 4);                          \
  int ks2_ = (((lane & 7) ^ (lane >> 3)) << 3);                              \
  u16* Lw_ = lds + ((tid >> 6) << 10);                                       \
  int rA_ = wr * 32 + (lane & 31), rB_ = wc * 32 + (lane & 31);              \
  int kh_ = lane >> 5;                                                       \
  f32x16 accR = {};                                                          \
  f32x16 accI = {};

#define CG_STAGE(buf, k0, PAr, PAi, PBr, PBi)                                \
  { u16* Lb = Lw_ + (buf) * (4 * PSZ2);                                      \
    gload16((PAr) + (size_t)(bm + lr8_) * 1024 + (k0) + ks2_,     Lb + 0 * PSZ2);       \
    gload16((PAr) + (size_t)(bm + lr8_ + 8) * 1024 + (k0) + ks2_, Lb + 0 * PSZ2 + 512); \
    gload16((PAi) + (size_t)(bm + lr8_) * 1024 + (k0) + ks2_,     Lb + 1 * PSZ2);       \
    gload16((PAi) + (size_t)(bm + lr8_ + 8) * 1024 + (k0) + ks2_, Lb + 1 * PSZ2 + 512); \
    gload16((PBr) + (size_t)(bn + lr8_) * 1024 + (k0) + ks2_,     Lb + 2 * PSZ2);       \
    gload16((PBr) + (size_t)(bn + lr8_ + 8) * 1024 + (k0) + ks2_, Lb + 2 * PSZ2 + 512); \
    gload16((PBi) + (size_t)(bn + lr8_) * 1024 + (k0) + ks2_,     Lb + 3 * PSZ2);       \
    gload16((PBi) + (size_t)(bn + lr8_ + 8) * 1024 + (k0) + ks2_, Lb + 3 * PSZ2 + 512); }

// one k-slice (K=16) of the complex product, 32x32x16
#define CG_SLICE(L, s, BNEG)                                                 \
  { bf8v ar = fragld32((L) + 0 * PSZ2, rA_, s, kh_);                         \
    bf8v ai = fragld32((L) + 1 * PSZ2, rA_, s, kh_);                         \
    bf8v br = fragld32((L) + 2 * PSZ2, rB_, s, kh_);                         \
    bf8v bi = fragld32((L) + 3 * PSZ2, rB_, s, kh_);                         \
    if (BNEG == 0) {                                                         \
      bf8v nbr = neg8(br), nbi = neg8(bi);                                   \
      accR = __builtin_amdgcn_mfma_f32_32x32x16_bf16(ar, nbr, accR, 0, 0, 0);\
      accR = __builtin_amdgcn_mfma_f32_32x32x16_bf16(ai, nbi, accR, 0, 0, 0);\
      accI = __builtin_amdgcn_mfma_f32_32x32x16_bf16(ar, bi,  accI, 0, 0, 0);\
      accI = __builtin_amdgcn_mfma_f32_32x32x16_bf16(ai, nbr, accI, 0, 0, 0);\
    } else {                                                                 \
      bf8v nbi = neg8(bi);                                                   \
      accR = __builtin_amdgcn_mfma_f32_32x32x16_bf16(ar, br,  accR, 0, 0, 0);\
      accR = __builtin_amdgcn_mfma_f32_32x32x16_bf16(ai, bi,  accR, 0, 0, 0);\
      accI = __builtin_amdgcn_mfma_f32_32x32x16_bf16(ar, nbi, accI, 0, 0, 0);\
      accI = __builtin_amdgcn_mfma_f32_32x32x16_bf16(ai, br,  accI, 0, 0, 0);\
    } }

#define CG_PIPELINE(BNEG, PAr, PAi, PBr, PBi)                                \
  CG_STAGE(0, 0, PAr, PAi, PBr, PBi);                                        \
  _Pragma("unroll 1")                                                        \
  for (int t = 0; t < 16; ++t) {                                             \
    int bufc = t & 1;                                                        \
    if (t + 1 < 16) { CG_STAGE(bufc ^ 1, (t + 1) * 64, PAr, PAi, PBr, PBi);  \
                      WAITV(8); }                                            \
    else            { WAITV(0); }                                            \
    __builtin_amdgcn_sched_barrier(0);                                       \
    __builtin_amdgcn_s_barrier();                                            \
    { const u16* L = lds + bufc * (4 * PSZ2);                                \
      CG_SLICE(L, 0, BNEG) CG_SLICE(L, 1, BNEG)                              \
      CG_SLICE(L, 2, BNEG) CG_SLICE(L, 3, BNEG) }                            \
    __builtin_amdgcn_sched_barrier(0);                                       \
    __builtin_amdgcn_s_barrier();                                            \
  }

// C/D mapping (32x32): col = lane&31, row = (j&3) + 8*(j>>2) + 4*kh_
#define CG_ROWCOL(j)                                                         \
  int rowg = bm + wr * 32 + ((j) & 3) + 8 * ((j) >> 2) + 4 * kh_;            \
  int col  = bn + wc * 32 + (lane & 31);

// --- A2 = A@A  (BNEG0, bf16 out) -------------------------------------------
__global__ __launch_bounds__(TPB) void cgemm_a2_k(
    const u16* __restrict__ Apr, const u16* __restrict__ Api,
    u16* __restrict__ Cr16, u16* __restrict__ Ci16)
{
  int flat = swz8(blockIdx.x, 256);
  int bm = (flat >> 4) * 64, bn = (flat & 15) * 64;
  CG_PRELUDE
  CG_PIPELINE(0, Apr, Api, Apr, Api)
  #pragma unroll
  for (int j = 0; j < 16; ++j) {
    CG_ROWCOL(j)
    size_t o = (size_t)rowg * 1024 + col;
    Cr16[o] = f2bf(accR[j]);
    Ci16[o] = f2bf(accI[j]);
  }
}

// --- batched: z=0: A4 = A2@A2 ; z=1: T1 = N@A2 + N   (BNEG1, bf16 out) -----
__global__ __launch_bounds__(TPB) void cgemm_pair_k(
    const u16* __restrict__ A2r, const u16* __restrict__ A2i,
    const u16* __restrict__ Nr2, const u16* __restrict__ Ni2,
    u16* __restrict__ A4r, u16* __restrict__ A4i,
    u16* __restrict__ T1r, u16* __restrict__ T1i)
{
  int flat = swz8(blockIdx.x, 512);
  int z = flat >> 8;
  int t8 = flat & 255;
  int bm = (t8 >> 4) * 64, bn = (t8 & 15) * 64;
  const u16* Apr = z ? Nr2 : A2r;
  const u16* Api = z ? Ni2 : A2i;
  u16* Cr16 = z ? T1r : A4r;
  u16* Ci16 = z ? T1i : A4i;
  CG_PRELUDE
  CG_PIPELINE(1, Apr, Api, A2r, A2i)
  #pragma unroll
  for (int j = 0; j < 16; ++j) {
    CG_ROWCOL(j)
    size_t o = (size_t)rowg * 1024 + col;
    float vr = accR[j], vi = accI[j];
    if (z) { vr += bf2f(Nr2[o]); vi += bf2f(Ni2[o]); }   // +N
    Cr16[o] = f2bf(vr);
    Ci16[o] = f2bf(vi);
  }
}

// --- V = 2*(T1@A4) + 2*T1 - I   (BNEG1, f32 out) ---------------------------
__global__ __launch_bounds__(TPB) void cgemm_v_k(
    const u16* __restrict__ T1r, const u16* __restrict__ T1i,
    const u16* __restrict__ A4r, const u16* __restrict__ A4i,
    float* __restrict__ Vr, float* __restrict__ Vi)
{
  int flat = swz8(blockIdx.x, 256);
  int bm = (flat >> 4) * 64, bn = (flat & 15) * 64;
  CG_PRELUDE
  CG_PIPELINE(1, T1r, T1i, A4r, A4i)
  #pragma unroll
  for (int j = 0; j < 16; ++j) {
    CG_ROWCOL(j)
    size_t o = (size_t)rowg * 1024 + col;
    float dg = (rowg == col) ? 1.0f : 0.0f;
    Vr[o] = 2.0f * accR[j] + 2.0f * bf2f(T1r[o]) - dg;
    Vi[o] = 2.0f * accI[j] + 2.0f * bf2f(T1i[o]);
  }
}

// ---------------------------------------------------------------------------
// Mt[d][k] = bf16( V[k][d]*exp(ls[d])*(1-alpha) + F[k][d]*alpha/32 )
// ---------------------------------------------------------------------------
__global__ __launch_bounds__(TPB) void build_mt_k(
    const float* __restrict__ Vr, const float* __restrict__ Vi,
    const float* __restrict__ log_sigma, const float* __restrict__ dft_weight,
    u16* __restrict__ Mtr, u16* __restrict__ Mti)
{
  __shared__ float Tr[64][65], Ti[64][65];
  int tid = threadIdx.x;
  int k0 = blockIdx.x * 64, d0 = blockIdx.y * 64;
  int c = tid & 63, r4 = tid >> 6;
  for (int p = 0; p < 16; ++p) {
    int r = r4 + p * 4;                       // local k index
    Tr[r][c] = Vr[(size_t)(k0 + r) * 1024 + d0 + c];
    Ti[r][c] = Vi[(size_t)(k0 + r) * 1024 + d0 + c];
  }
  __syncthreads();
  float alpha = sigmoidf_(dft_weight[0]);
  const float isq = 0.03125f * alpha;
  for (int p = 0; p < 16; ++p) {
    int dl = r4 + p * 4;                      // local d index (output row)
    int d = d0 + dl, k = k0 + c;
    float w1 = expf(log_sigma[d]) * (1.0f - alpha);
    int mm = (k * d) & 1023;
    float ang = -6.283185307179586f * (float)mm * (1.0f / 1024.0f);
    float sn, cs;
    sincosf(ang, &sn, &cs);
    size_t o = (size_t)d * 1024 + k;
    Mtr[o] = f2bf(Tr[c][dl] * w1 + cs * isq);
    Mti[o] = f2bf(Ti[c][dl] * w1 + sn * isq);
  }
}

// ---------------------------------------------------------------------------
// X f32 -> bf16 plane (vectorized, once)
// ---------------------------------------------------------------------------
__global__ __launch_bounds__(TPB) void xconv_k(
    const float* __restrict__ X, u16* __restrict__ Xb)
{
  int idx = (blockIdx.x * TPB + threadIdx.x) << 3;    // 8 per thread
  float4 a = *(const float4*)(X + idx);
  float4 b = *(const float4*)(X + idx + 4);
  u16 tmp[8];
  pack8(a, b, tmp);
  *(bf8v*)(Xb + idx) = *(bf8v*)tmp;
}

// ---------------------------------------------------------------------------
// per-d constants: op_decay, op_forcing, base_var
// ---------------------------------------------------------------------------
__global__ __launch_bounds__(TPB) void prep_k(
    const float* __restrict__ ld, const float* __restrict__ lf,
    const float* __restrict__ law_re, const float* __restrict__ law_im,
    const float* __restrict__ dt, const float* __restrict__ base_noise,
    float* __restrict__ od_re, float* __restrict__ od_im,
    float* __restrict__ of_re, float* __restrict__ of_im,
    float* __restrict__ bvar)
{
  int d = blockIdx.x * TPB + threadIdx.x;
  float dtr = dt[0];                              // DT_REF = 1.0
  float lre = tanhf(-expf(ld[d]) + law_re[d]) * 0.3f;
  float lim = lf[d] + law_im[d];
  float er = expf(lre * dtr);
  float sn, cs;
  sincosf(lim * dtr, &sn, &cs);
  float odr = er * cs, odi = er * sn;
  od_re[d] = odr;  od_im[d] = odi;
  float numr = odr - 1.0f, numi = odi;
  float denr = lre + 1e-8f, deni = lim;
  float inv = 1.0f / (denr * denr + deni * deni);
  of_re[d] = (numr * denr + numi * deni) * inv;
  of_im[d] = (numi * denr - numr * deni) * inv;
  float bn = base_noise[0];
  float bv = bn * bn * expm1f(2.0f * lre * dtr) / (2.0f * lre + 1e-8f);
  bvar[d] = fmaxf(bv, 0.0f);
}

// ---------------------------------------------------------------------------
// Wu1, Wu2 f32 -> bf16 planes
// ---------------------------------------------------------------------------
__global__ __launch_bounds__(TPB) void conv_w_k(
    const float* __restrict__ Wu1, const float* __restrict__ Wu2,
    u16* __restrict__ Wu1b, u16* __restrict__ Wu2b)
{
  int idx = blockIdx.x * TPB + threadIdx.x;     // 2 * 262144
  if (idx < 262144) Wu1b[idx] = f2bf(Wu1[idx]);
  else              Wu2b[idx - 262144] = f2bf(Wu2[idx - 262144]);
}

// ---------------------------------------------------------------------------
// M=16 split-K MFMA GEMM (partials) ; reduce adds bias (+sigmoid)
// ---------------------------------------------------------------------------
__global__ __launch_bounds__(TPB) void sgemm16_k(
    const float* __restrict__ A0, const float* __restrict__ A1,
    const float* __restrict__ Bw, float* __restrict__ Pp, int N)
{
  __shared__ __align__(16) u16 lds[2 * BUF1];
  int tid = threadIdx.x;
  int c0 = blockIdx.x * 64;
  int kbase = blockIdx.y * 256;
  int lane = tid & 63;
  int w = tid >> 6;
  int row = tid >> 2, kq = (tid & 3) << 3;

  f32x4 acc = {};
  float4 pb0, pb1;

  auto gload = [&](int k0) {
    const float* p = Bw + (size_t)(c0 + row) * 2048 + k0 + kq;
    pb0 = *(const float4*)p; pb1 = *(const float4*)(p + 4);
  };
  auto stolds = [&](int buf) {
    pack8(pb0, pb1, lds + buf * BUF1 + row * LSTR + kq);
  };
  auto compute = [&](int buf, int k0) {
    int ar = lane & 15;
    int ko = (lane >> 4) * 8;
    const float* ap = (k0 < 1024) ? (A0 + (size_t)ar * 1024 + k0 + ko)
                                  : (A1 + (size_t)ar * 1024 + k0 + ko - 1024);
    float4 a0 = *(const float4*)ap, a1 = *(const float4*)(ap + 4);
    u16 abuf[8];
    pack8(a0, a1, abuf);
    bf8v af = *(bf8v*)abuf;
    const u16* L = lds + buf * BUF1;
    bf8v bfr = *(const bf8v*)(L + (w * 16 + (lane & 15)) * LSTR + ko);
    acc = __builtin_amdgcn_mfma_f32_16x16x32_bf16(af, bfr, acc, 0, 0, 0);
  };

  gload(kbase); stolds(0); __syncthreads();
  int cur = 0;
  for (int t = 0; t < 8; ++t) {
    int k0 = kbase + t * 32;
    if (t < 7) gload(k0 + 32);
    compute(cur, k0);
    if (t < 7) stolds(cur ^ 1);
    __syncthreads();
    cur ^= 1;
  }

  int c = c0 + w * 16 + (lane & 15);
  #pragma unroll
  for (int r = 0; r < 4; ++r) {
    int rr = (lane >> 4) * 4 + r;
    Pp[((size_t)blockIdx.y * 16 + rr) * N + c] = acc[r];
  }
}

__global__ __launch_bounds__(TPB) void red16_k(
    const float* __restrict__ Pp, const float* __restrict__ bias,
    float* __restrict__ out, int N, int act)
{
  int idx = blockIdx.x * TPB + threadIdx.x;   // 16*N
  int c = idx & (N - 1);
  float v = bias[c];
  #pragma unroll
  for (int s = 0; s < 8; ++s) v += Pp[(size_t)s * 16 * N + idx];
  if (act == 1) v = sigmoidf_(v);
  out[idx] = v;
}

// ---------------------------------------------------------------------------
// flux_next = flux*fdecay + update ; FN planes + f32 output 1 = Re(flux_next)
// ---------------------------------------------------------------------------
__global__ __launch_bounds__(TPB) void flux_k(
    const float* __restrict__ xin,
    const float* __restrict__ flux_re, const float* __restrict__ flux_im,
    const float* __restrict__ decay_re, const float* __restrict__ decay_im,
    float* __restrict__ FNr, float* __restrict__ FNi,
    float* __restrict__ out1)
{
  int idx = blockIdx.x * TPB + threadIdx.x;     // 16 * 1024
  int b = idx >> 10, d = idx & 1023;
  float fdr = sigmoidf_(decay_re[d]);
  float fdi = decay_im[d];
  float fr = flux_re[idx], fi = flux_im[idx];
  float ur = xin[b * 2048 + d], ui = xin[b * 2048 + 1024 + d];
  float nr = fr * fdr - fi * fdi + ur;
  float ni = fr * fdi + fi * fdr + ui;
  FNr[idx] = nr;  FNi[idx] = ni;
  out1[idx] = nr;                                // f32, real part only
}

// ---------------------------------------------------------------------------
// x_tilde = Xb @ M + h_next epilogue -> Hrb bf16 (BK=64, 32x32x16 MFMA)
// ---------------------------------------------------------------------------
__global__ __launch_bounds__(TPB) void xmh_nt_k(
    const u16* __restrict__ Xb,
    const u16* __restrict__ Mtr, const u16* __restrict__ Mti,
    const float* __restrict__ gate, const float* __restrict__ proj,
    const float* __restrict__ od_re, const float* __restrict__ od_im,
    const float* __restrict__ of_re, const float* __restrict__ of_im,
    const float* __restrict__ hp_re, const float* __restrict__ hp_im,
    u16* __restrict__ Hrb)
{
  __shared__ __align__(16) u16 lds[2 * 3 * PSZ2];     // 48KB
  int flat = swz8(blockIdx.x, 1024);
  int bm = (flat >> 4) * 64, bn = (flat & 15) * 64;
  int tid = threadIdx.x;
  int lane = tid & 63;
  int wr = (tid >> 7) & 1, wc = (tid >> 6) & 1;
  int lr8_ = ((tid & 63) >> 3) + ((tid >> 6) << 4);
  int ks2_ = (((lane & 7) ^ (lane >> 3)) << 3);
  u16* Lw_ = lds + ((tid >> 6) << 10);
  int rA_ = wr * 32 + (lane & 31), rB_ = wc * 32 + (lane & 31);
  int kh_ = lane >> 5;

  f32x16 accR = {};
  f32x16 accI = {};

#define XM_STAGE(buf, k0)                                                    \
  { u16* Lb = Lw_ + (buf) * (3 * PSZ2);                                      \
    gload16(Xb  + (size_t)(bm + lr8_) * 1024 + (k0) + ks2_,     Lb + 0 * PSZ2);       \
    gload16(Xb  + (size_t)(bm + lr8_ + 8) * 1024 + (k0) + ks2_, Lb + 0 * PSZ2 + 512); \
    gload16(Mtr + (size_t)(bn + lr8_) * 1024 + (k0) + ks2_,     Lb + 1 * PSZ2);       \
    gload16(Mtr + (size_t)(bn + lr8_ + 8) * 1024 + (k0) + ks2_, Lb + 1 * PSZ2 + 512); \
    gload16(Mti + (size_t)(bn + lr8_) * 1024 + (k0) + ks2_,     Lb + 2 * PSZ2);       \
    gload16(Mti + (size_t)(bn + lr8_ + 8) * 1024 + (k0) + ks2_, Lb + 2 * PSZ2 + 512); }
#define XM_SLICE(L, s)                                                       \
  { bf8v a  = fragld32((L) + 0 * PSZ2, rA_, s, kh_);                         \
    bf8v br = fragld32((L) + 1 * PSZ2, rB_, s, kh_);                         \
    bf8v bi = fragld32((L) + 2 * PSZ2, rB_, s, kh_);                         \
    accR = __builtin_amdgcn_mfma_f32_32x32x16_bf16(a, br, accR, 0, 0, 0);    \
    accI = __builtin_amdgcn_mfma_f32_32x32x16_bf16(a, bi, accI, 0, 0, 0); }

  XM_STAGE(0, 0);
  #pragma unroll 1
  for (int t = 0; t < 16; ++t) {
    int bufc = t & 1;
    if (t + 1 < 16) { XM_STAGE(bufc ^ 1, (t + 1) * 64); WAITV(6); }
    else            { WAITV(0); }
    __builtin_amdgcn_sched_barrier(0);
    __builtin_amdgcn_s_barrier();
    { const u16* L = lds + bufc * (3 * PSZ2);
      XM_SLICE(L, 0) XM_SLICE(L, 1) XM_SLICE(L, 2) XM_SLICE(L, 3) }
    __builtin_amdgcn_sched_barrier(0);
    __builtin_amdgcn_s_barrier();
  }

  #pragma unroll
  for (int j = 0; j < 16; ++j) {
    int t = bm + wr * 32 + (j & 3) + 8 * (j >> 2) + 4 * kh_;
    int c = bn + wc * 32 + (lane & 31);
    int b = t >> 8;                         // 64-row tile never straddles batch
    float g  = gate[b * 1024 + c];
    float sr = proj[b * 2048 + c];
    float si = proj[b * 2048 + 1024 + c];
    float fr = accR[j] * g + sr * (1.0f - g);
    float fi = accI[j] * g + si * (1.0f - g);
    float odr = od_re[c], odi = od_im[c];
    float ofr = of_re[c], ofi = of_im[c];
    size_t off = (size_t)t * 1024 + c;
    float pr = hp_re[off], pi = hp_im[off];
    Hrb[off] = f2bf(pr * odr - pi * odi + fr * ofr - fi * ofi);
  }
}

// ---------------------------------------------------------------------------
// real NT GEMM, bf16: C = A@B^T.  KI = K/32.  3-buffer counted-vmcnt, BK=32.
// EPI=0 (mlp1): silu->bf16 direct.  EPI=2 (u): softplus->bf16 via LDS tile.
// ---------------------------------------------------------------------------
template<int KI, int EPI>
__global__ __launch_bounds__(TPB) void rgemm_nt_k(
    const u16* __restrict__ A, const u16* __restrict__ B,
    const float* __restrict__ bias,
    u16* __restrict__ C16, int nbxl, int total)
{
  __shared__ __align__(16) u16 lds[3 * 2 * PSZ];   // 24KB (ct needs 17.4KB)
  const int K = KI * 32;
  int tid = threadIdx.x;
  int flat = swz8(blockIdx.x, total);
  int bm = (flat >> nbxl) * 64;
  int bn = (flat & ((1 << nbxl) - 1)) * 64;
  const int N = 64 << nbxl;
  int lane = tid & 63;
  int wr = (tid >> 7) & 1, wc = (tid >> 6) & 1;
  int lr_ = ((tid & 63) >> 2) + ((tid >> 6) << 4);
  int ks_ = (((tid & 3) ^ ((tid >> 3) & 3)) << 3);
  u16* Lw_ = lds + ((tid >> 6) << 9);

  f32x4 acc[2][2] = {};

#define RG_STAGE(buf, k0)                                                    \
  { u16* Lb = Lw_ + (buf) * (2 * PSZ);                                       \
    gload16(A + (size_t)(bm + lr_) * K + (k0) + ks_, Lb + 0 * PSZ);          \
    gload16(B + (size_t)(bn + lr_) * K + (k0) + ks_, Lb + 1 * PSZ); }
#define RG_COMPUTE(buf)                                                      \
  { const u16* L = lds + (buf) * (2 * PSZ);                                  \
    int rA = wr * 32 + (lane & 15);                                          \
    int rB = wc * 32 + (lane & 15);                                          \
    int kq = lane >> 4;                                                      \
    bf8v a[2], b[2];                                                         \
    a[0] = fragld(L + 0 * PSZ, rA, kq);  a[1] = fragld(L + 0 * PSZ, rA + 16, kq); \
    b[0] = fragld(L + 1 * PSZ, rB, kq);  b[1] = fragld(L + 1 * PSZ, rB + 16, kq); \
    _Pragma("unroll")                                                        \
    for (int mf = 0; mf < 2; ++mf)                                           \
      _Pragma("unroll")                                                      \
      for (int nf = 0; nf < 2; ++nf)                                         \
        acc[mf][nf] = __builtin_amdgcn_mfma_f32_16x16x32_bf16(a[mf], b[nf], acc[mf][nf], 0, 0, 0); }

  RG_STAGE(0, 0);
  RG_STAGE(1, 32);
  #pragma unroll 1
  for (int t = 0; t < KI; ++t) {
    int bufc = t % 3;
    if (t + 2 < KI) { RG_STAGE((t + 2) % 3, (t + 2) * 32); }
    if (t + 2 < KI)      { WAITV(4); }
    else if (t + 1 < KI) { WAITV(2); }
    else                 { WAITV(0); }
    __builtin_amdgcn_sched_barrier(0);
    __builtin_amdgcn_s_barrier();
    RG_COMPUTE(bufc)
    __builtin_amdgcn_sched_barrier(0);
    __builtin_amdgcn_s_barrier();
  }

  if constexpr (EPI == 0) {
    #pragma unroll
    for (int mf = 0; mf < 2; ++mf)
      #pragma unroll
      for (int nf = 0; nf < 2; ++nf) {
        int c = bn + wc * 32 + nf * 16 + (lane & 15);
        #pragma unroll
        for (int r = 0; r < 4; ++r) {
          int t = bm + wr * 32 + mf * 16 + (lane >> 4) * 4 + r;
          float v = acc[mf][nf][r] + bias[c];
          v = v * sigmoidf_(v);                       // silu (fast exp)
          C16[(size_t)t * N + c] = f2bf(v);
        }
      }
  } else {
    // acc -> LDS f32 tile, then row-contiguous packed-bf16 softplus stores
    float* ct = (float*)lds;
    __syncthreads();
    #pragma unroll
    for (int mf = 0; mf < 2; ++mf)
      #pragma unroll
      for (int nf = 0; nf < 2; ++nf) {
        int rbase = wr * 32 + mf * 16 + (lane >> 4) * 4;
        int cc = wc * 32 + nf * 16 + (lane & 15);
        #pragma unroll
        for (int r = 0; r < 4; ++r)
          ct[(rbase + r) * CSTR + cc] = acc[mf][nf][r];
      }
    __syncthreads();
    int w = tid >> 6, l = tid & 63;
    int lcol = (l & 15) * 4;
    #pragma unroll
    for (int p = 0; p < 4; ++p) {
      int lrow = w * 16 + p * 4 + (l >> 4);
      int t = bm + lrow;
      int c = bn + lcol;
      float4 v4 = *(float4*)&ct[lrow * CSTR + lcol];
      float4 bi4 = *(const float4*)(bias + c);
      float u0 = spf_(v4.x + bi4.x);
      float u1 = spf_(v4.y + bi4.y);
      float u2 = spf_(v4.z + bi4.z);
      float u3 = spf_(v4.w + bi4.w);
      *(uint2*)(C16 + (size_t)t * N + c) = packbf4(u0, u1, u2, u3);
    }
  }
}

// ---------------------------------------------------------------------------
// out0 = Hrb + nre * sqrt(bvar * u) * sqrt(0.5)   (pure elementwise, x8)
// ---------------------------------------------------------------------------
__global__ __launch_bounds__(TPB) void fin_k(
    const u16* __restrict__ Hrb, const u16* __restrict__ ub,
    const float* __restrict__ nre, const float* __restrict__ bvar,
    float* __restrict__ out0)
{
  int idx = (blockIdx.x * TPB + threadIdx.x) << 3;    // 8 per thread
  int c = idx & 1023;
  bf8v hb = *(const bf8v*)(Hrb + idx);
  bf8v uv = *(const bf8v*)(ub + idx);
  float4 n0 = *(const float4*)(nre + idx);
  float4 n1 = *(const float4*)(nre + idx + 4);
  float4 b0 = *(const float4*)(bvar + c);
  float4 b1 = *(const float4*)(bvar + c + 4);
  float4 o0, o1;
  const float s2 = 0.7071067811865476f;
  #pragma unroll
  for (int j = 0; j < 4; ++j) {
    float sc = sqrtf(((const float*)&b0)[j] * bf2f((u16)uv[j])) * s2;
    ((float*)&o0)[j] = bf2f((u16)hb[j]) + ((const float*)&n0)[j] * sc;
  }
  #pragma unroll
  for (int j = 0; j < 4; ++j) {
    float sc = sqrtf(((const float*)&b1)[j] * bf2f((u16)uv[4 + j])) * s2;
    ((float*)&o1)[j] = bf2f((u16)hb[4 + j]) + ((const float*)&n1)[j] * sc;
  }
  *(float4*)(out0 + idx)     = o0;
  *(float4*)(out0 + idx + 4) = o1;
}

// ---------------------------------------------------------------------------
extern "C" void kernel_launch(void* const* d_in, const int* in_sizes, int n_in,
                              void* d_out, int out_size, void* d_ws, size_t ws_size,
                              hipStream_t stream) {
  (void)in_sizes; (void)n_in; (void)out_size;

  const float* x_input    = (const float*)d_in[0];
  const float* h_prev_re  = (const float*)d_in[1];
  const float* h_prev_im  = (const float*)d_in[2];
  const float* xg_re      = (const float*)d_in[3];
  const float* xg_im      = (const float*)d_in[4];
  const float* flux_re    = (const float*)d_in[5];
  const float* flux_im    = (const float*)d_in[6];
  const float* dt         = (const float*)d_in[7];
  const float* v_raw_re   = (const float*)d_in[10];
  const float* v_raw_im   = (const float*)d_in[11];
  const float* log_sigma  = (const float*)d_in[12];
  const float* dft_weight = (const float*)d_in[13];
  const float* decay_re   = (const float*)d_in[14];
  const float* decay_im   = (const float*)d_in[15];
  const float* Wi_in      = (const float*)d_in[16];
  const float* bi         = (const float*)d_in[17];
  const float* Wo         = (const float*)d_in[18];
  const float* bo         = (const float*)d_in[19];
  const float* Wg         = (const float*)d_in[20];
  const float* bg         = (const float*)d_in[21];
  const float* ld         = (const float*)d_in[22];
  const float* lf         = (const float*)d_in[23];
  const float* law_re     = (const float*)d_in[24];
  const float* law_im     = (const float*)d_in[25];
  const float* base_noise = (const float*)d_in[26];
  const float* Wu1        = (const float*)d_in[27];
  const float* bu1        = (const float*)d_in[28];
  const float* Wu2        = (const float*)d_in[29];
  const float* bu2        = (const float*)d_in[30];
  const float* noise_re   = (const float*)d_in[31];

  // --- workspace: 16 bf16-sized planes (2MB each) = 32MB --------------------
  const size_t PL16 = 1024ull * 1024ull;        // u16 per plane
  if (ws_size < 16 * PL16 * 2) return;          // too small -> zeros (diagnostic)

  u16* P = (u16*)d_ws;
  u16* Ar  = P + 0 * PL16;   u16* Ai  = P + 1 * PL16;   // A       (dead after A2)
  u16* Nr  = P + 2 * PL16;   u16* Ni  = P + 3 * PL16;   // N = I-A (dead after pair)
  u16* A2r = P + 4 * PL16;   u16* A2i = P + 5 * PL16;   // dead after pair
  u16* A4r = P + 6 * PL16;   u16* A4i = P + 7 * PL16;   // dead after V
  u16* T1r = P + 8 * PL16;   u16* T1i = P + 9 * PL16;   // dead after V
  // liveness reuse (stream-ordered):
  float* Vr = (float*)(P + 0 * PL16);   // 8MB over P0..P3 (A,N dead)
  float* Vi = (float*)(P + 2 * PL16);
  u16* Mtr  = P + 8 * PL16;             // over T1 (dead after V)
  u16* Mti  = P + 9 * PL16;
  u16* Xb   = P + 4 * PL16;             // 8MB over A2,A4 (dead after V)
  float* Pp = (float*)(P + 0 * PL16);   // 1MB split-K partials (V dead after build_mt)
  u16* ub   = P + 0 * PL16;             // 8MB u-plane (Pp dead after red16 chain)
  u16* Hrb  = P + 10 * PL16;            // 8MB, P10..P13
  u16* mlp1b = P + 14 * PL16;           // 4096x256
  u16* Wu1b  = P + 15 * PL16;           // 262144 u16
  u16* Wu2b  = Wu1b + 262144;
  float* sm  = (float*)(P + 15 * PL16 + 524288);
  float* xin  = sm;                     // 16x2048
  float* proj = xin + 32768;            // 16x2048
  float* FNr  = proj + 32768;           // 16x1024
  float* FNi  = FNr + 16384;
  float* gate = FNi + 16384;            // 16x1024
  float* od_re = gate + 16384;
  float* od_im = od_re + 1024;
  float* of_re = od_im + 1024;
  float* of_im = of_re + 1024;
  float* bvar  = of_im + 1024;

  float* out0f = (float*)d_out;                       // 4096x1024 f32 (real)
  float* out1f = out0f + (size_t)4096 * 1024;         // 16x1024 f32 (real)

  // --- Cayley: V = 2*(I-A)(I+A^2)(I+A^4) - I, err <= 2.2e-3 -----------------
  build_a_k<<<4096, TPB, 0, stream>>>(v_raw_re, v_raw_im, Ar, Ai, Nr, Ni);
  cgemm_a2_k<<<256, TPB, 0, stream>>>(Ar, Ai, A2r, A2i);                 // A2 = A@A
  cgemm_pair_k<<<512, TPB, 0, stream>>>(A2r, A2i, Nr, Ni,                // A4 = A2@A2
                                        A4r, A4i, T1r, T1i);             // T1 = N@A2+N
  cgemm_v_k<<<256, TPB, 0, stream>>>(T1r, T1i, A4r, A4i, Vr, Vi);        // V
  build_mt_k<<<dim3(16, 16), TPB, 0, stream>>>(Vr, Vi, log_sigma, dft_weight, Mtr, Mti);
  xconv_k<<<2048, TPB, 0, stream>>>(x_input, Xb);

  // --- per-d constants + weight conversion ----------------------------------
  prep_k<<<4, TPB, 0, stream>>>(ld, lf, law_re, law_im, dt, base_noise,
                                od_re, od_im, of_re, of_im, bvar);
  conv_w_k<<<2048, TPB, 0, stream>>>(Wu1, Wu2, Wu1b, Wu2b);

  // --- B=16 chain: split-K MFMA gemms ---------------------------------------
  sgemm16_k<<<dim3(32, 8), TPB, 0, stream>>>(xg_re, xg_im, Wi_in, Pp, 2048);
  red16_k<<<128, TPB, 0, stream>>>(Pp, bi, xin, 2048, 0);
  flux_k<<<64, TPB, 0, stream>>>(xin, flux_re, flux_im, decay_re, decay_im,
                                 FNr, FNi, out1f);
  sgemm16_k<<<dim3(32, 8), TPB, 0, stream>>>(FNr, FNi, Wo, Pp, 2048);
  red16_k<<<128, TPB, 0, stream>>>(Pp, bo, proj, 2048, 0);
  sgemm16_k<<<dim3(16, 8), TPB, 0, stream>>>(FNr, FNi, Wg, Pp, 1024);
  red16_k<<<64, TPB, 0, stream>>>(Pp, bg, gate, 1024, 1);

  // --- x_tilde = Xb@M fused with h_next epilogue -> Hrb bf16 ----------------
  xmh_nt_k<<<1024, TPB, 0, stream>>>(Xb, Mtr, Mti, gate, proj,
                                     od_re, od_im, of_re, of_im,
                                     h_prev_re, h_prev_im, Hrb);

  // --- u-MLP (MFMA) + elementwise final -------------------------------------
  rgemm_nt_k<32, 0><<<256, TPB, 0, stream>>>(Hrb, Wu1b, bu1, mlp1b, 2, 256);
  rgemm_nt_k<8, 2><<<1024, TPB, 0, stream>>>(mlp1b, Wu2b, bu2, ub, 4, 1024);
  fin_k<<<2048, TPB, 0, stream>>>(Hrb, ub, noise_re, bvar, out0f);
}

// Round 17
// 177.588 us; speedup vs baseline: 1.0339x; 1.0339x over previous
//
#include <hip/hip_runtime.h>
#include <cstddef>

#define TPB 256

typedef short bf8v  __attribute__((ext_vector_type(8)));   // 8 bf16 bit-patterns
typedef float f32x4 __attribute__((ext_vector_type(4)));
typedef unsigned short u16;

#define PSZ 2048     // u16 per LDS plane [64][32] (rgemm staging)
#define PSZ2 4096    // u16 per LDS plane [64][64] (BK=64 staging)
#define LSTR 40      // legacy stride for sgemm16 staging
#define BUF1 2560
#define CSTR 68      // f32 LDS epilogue-tile row stride

static __device__ __forceinline__ u16 f2bf(float x) {
  unsigned int u = __float_as_uint(x);
  u = (u + 0x7FFFu + ((u >> 16) & 1u)) >> 16;   // RNE f32 -> bf16
  return (u16)u;
}
static __device__ __forceinline__ float bf2f(u16 x) {
  return __uint_as_float(((unsigned int)x) << 16);
}
static __device__ __forceinline__ float sigmoidf_(float x) {
  return 1.0f / (1.0f + __expf(-x));            // fast exp (v_exp_f32)
}
static __device__ __forceinline__ float spf_(float v) {   // fast softplus
  return (v > 15.0f) ? v : __logf(1.0f + __expf(v));
}
static __device__ __forceinline__ bf8v neg8(bf8v a) {
  #pragma unroll
  for (int i = 0; i < 8; ++i) a[i] ^= (short)0x8000;
  return a;
}
static __device__ __forceinline__ void pack8(const float4& x, const float4& y,
                                             u16* dst) {
  unsigned int* d = (unsigned int*)dst;
  d[0] = ((unsigned)f2bf(x.y) << 16) | f2bf(x.x);
  d[1] = ((unsigned)f2bf(x.w) << 16) | f2bf(x.z);
  d[2] = ((unsigned)f2bf(y.y) << 16) | f2bf(y.x);
  d[3] = ((unsigned)f2bf(y.w) << 16) | f2bf(y.z);
}
static __device__ __forceinline__ uint2 packbf4(float a, float b, float c, float d) {
  uint2 r;
  r.x = ((unsigned)f2bf(b) << 16) | f2bf(a);
  r.y = ((unsigned)f2bf(d) << 16) | f2bf(c);
  return r;
}
// async global->LDS, 16B per lane; LDS dest is wave-uniform base + lane*16
static __device__ __forceinline__ void gload16(const u16* g, u16* l) {
  __builtin_amdgcn_global_load_lds((const __attribute__((address_space(1))) void*)g,
                                   (__attribute__((address_space(3))) void*)l,
                                   16, 0, 0);
}
// BK=32 fragment read with k-chunk XOR swizzle (rgemm path)
static __device__ __forceinline__ bf8v fragld(const u16* plane, int r, int kq) {
  int kb = (kq << 4) ^ (((r >> 1) & 3) << 4);
  return *(const bf8v*)(plane + r * 32 + (kb >> 1));
}
// BK=64 fragment read: global chunk (s*4+kq) at row r lives at chunk^(r&7)
static __device__ __forceinline__ bf8v fragld2(const u16* plane, int r, int kq, int s) {
  int ch = ((s << 2) + kq) ^ (r & 7);
  return *(const bf8v*)(plane + r * 64 + (ch << 3));
}
// XCD-aware bijective block swizzle (T % 8 == 0)
static __device__ __forceinline__ int swz8(int flat, int T) {
  return (flat & 7) * (T >> 3) + (flat >> 3);
}

#define WAITV(n) asm volatile("s_waitcnt vmcnt(" #n ")" ::: "memory")

// ---------------------------------------------------------------------------
// A = (v - v^T)re + i(v + v^T)im ; N = I - A   -> bf16 planes
// ---------------------------------------------------------------------------
__global__ __launch_bounds__(TPB) void build_a_k(
    const float* __restrict__ vre, const float* __restrict__ vim,
    u16* __restrict__ Ar, u16* __restrict__ Ai,
    u16* __restrict__ Nr, u16* __restrict__ Ni)
{
  int idx = blockIdx.x * TPB + threadIdx.x;
  int i = idx >> 10, j = idx & 1023;
  float ar = vre[idx] - vre[j * 1024 + i];
  float ai = vim[idx] + vim[j * 1024 + i];
  float dg = (i == j) ? 1.0f : 0.0f;
  Ar[idx] = f2bf(ar);       Ai[idx] = f2bf(ai);
  Nr[idx] = f2bf(dg - ar);  Ni[idx] = f2bf(-ai);
}

// ---------------------------------------------------------------------------
// complex-NT, BK=64, 2-buffer counted-vmcnt pipeline (16 phases, 32 MFMA each)
//   BNEG=0 (B-plane = A):     B_true = (-b^r, +b^i)
//   BNEG=1 (B-plane = A^2k):  B_true = (+b^r, -b^i)
// ---------------------------------------------------------------------------
#define CG_PRELUDE                                                           \
  __shared__ __align__(16) u16 lds[2 * 4 * PSZ2];       /* 64KB */           \
  int tid = threadIdx.x;                                                     \
  int lane = tid & 63;                                                       \
  int wr = (tid >> 7) & 1, wc = (tid >> 6) & 1;                              \
  int lr8_ = ((tid & 63) >> 3) + ((tid >> 6) << 4);     /* w*16 + lane>>3 */ \
  int ks2_ = (((lane & 7) ^ (lane >> 3)) << 3);                              \
  u16* Lw_ = lds + ((tid >> 6) << 10);                  /* w*16 rows * 64 */ \
  f32x4 accR[2][2] = {};                                                     \
  f32x4 accI[2][2] = {};

#define CG_STAGE(buf, k0, PAr, PAi, PBr, PBi)                                \
  { u16* Lb = Lw_ + (buf) * (4 * PSZ2);                                      \
    gload16((PAr) + (size_t)(bm + lr8_) * 1024 + (k0) + ks2_,     Lb + 0 * PSZ2);       \
    gload16((PAr) + (size_t)(bm + lr8_ + 8) * 1024 + (k0) + ks2_, Lb + 0 * PSZ2 + 512); \
    gload16((PAi) + (size_t)(bm + lr8_) * 1024 + (k0) + ks2_,     Lb + 1 * PSZ2);       \
    gload16((PAi) + (size_t)(bm + lr8_ + 8) * 1024 + (k0) + ks2_, Lb + 1 * PSZ2 + 512); \
    gload16((PBr) + (size_t)(bn + lr8_) * 1024 + (k0) + ks2_,     Lb + 2 * PSZ2);       \
    gload16((PBr) + (size_t)(bn + lr8_ + 8) * 1024 + (k0) + ks2_, Lb + 2 * PSZ2 + 512); \
    gload16((PBi) + (size_t)(bn + lr8_) * 1024 + (k0) + ks2_,     Lb + 3 * PSZ2);       \
    gload16((PBi) + (size_t)(bn + lr8_ + 8) * 1024 + (k0) + ks2_, Lb + 3 * PSZ2 + 512); }

#define CG_FRAGS(buf, s)                                                     \
  const u16* L = lds + (buf) * (4 * PSZ2);                                   \
  int rA = wr * 32 + (lane & 15);                                            \
  int rB = wc * 32 + (lane & 15);                                            \
  int kq = lane >> 4;                                                        \
  bf8v ar[2], ai[2], br[2], bi[2];                                           \
  ar[0] = fragld2(L + 0 * PSZ2, rA, kq, s);  ar[1] = fragld2(L + 0 * PSZ2, rA + 16, kq, s); \
  ai[0] = fragld2(L + 1 * PSZ2, rA, kq, s);  ai[1] = fragld2(L + 1 * PSZ2, rA + 16, kq, s); \
  br[0] = fragld2(L + 2 * PSZ2, rB, kq, s);  br[1] = fragld2(L + 2 * PSZ2, rB + 16, kq, s); \
  bi[0] = fragld2(L + 3 * PSZ2, rB, kq, s);  bi[1] = fragld2(L + 3 * PSZ2, rB + 16, kq, s);

#define CG_MFMA_BNEG0                                                        \
  { bf8v nbr[2] = { neg8(br[0]), neg8(br[1]) };                              \
    bf8v nbi[2] = { neg8(bi[0]), neg8(bi[1]) };                              \
    _Pragma("unroll")                                                        \
    for (int mf = 0; mf < 2; ++mf)                                           \
      _Pragma("unroll")                                                      \
      for (int nf = 0; nf < 2; ++nf) {                                       \
        accR[mf][nf] = __builtin_amdgcn_mfma_f32_16x16x32_bf16(ar[mf], nbr[nf], accR[mf][nf], 0, 0, 0); \
        accR[mf][nf] = __builtin_amdgcn_mfma_f32_16x16x32_bf16(ai[mf], nbi[nf], accR[mf][nf], 0, 0, 0); \
        accI[mf][nf] = __builtin_amdgcn_mfma_f32_16x16x32_bf16(ar[mf], bi[nf],  accI[mf][nf], 0, 0, 0); \
        accI[mf][nf] = __builtin_amdgcn_mfma_f32_16x16x32_bf16(ai[mf], nbr[nf], accI[mf][nf], 0, 0, 0); \
      } }

#define CG_MFMA_BNEG1                                                        \
  { bf8v nbi[2] = { neg8(bi[0]), neg8(bi[1]) };                              \
    _Pragma("unroll")                                                        \
    for (int mf = 0; mf < 2; ++mf)                                           \
      _Pragma("unroll")                                                      \
      for (int nf = 0; nf < 2; ++nf) {                                       \
        accR[mf][nf] = __builtin_amdgcn_mfma_f32_16x16x32_bf16(ar[mf], br[nf],  accR[mf][nf], 0, 0, 0); \
        accR[mf][nf] = __builtin_amdgcn_mfma_f32_16x16x32_bf16(ai[mf], bi[nf],  accR[mf][nf], 0, 0, 0); \
        accI[mf][nf] = __builtin_amdgcn_mfma_f32_16x16x32_bf16(ar[mf], nbi[nf], accI[mf][nf], 0, 0, 0); \
        accI[mf][nf] = __builtin_amdgcn_mfma_f32_16x16x32_bf16(ai[mf], br[nf],  accI[mf][nf], 0, 0, 0); \
      } }

#define CG_PIPELINE(MFMA_OP, PAr, PAi, PBr, PBi)                             \
  CG_STAGE(0, 0, PAr, PAi, PBr, PBi);                                        \
  _Pragma("unroll 1")                                                        \
  for (int t = 0; t < 16; ++t) {                                             \
    int bufc = t & 1;                                                        \
    if (t + 1 < 16) { CG_STAGE(bufc ^ 1, (t + 1) * 64, PAr, PAi, PBr, PBi);  \
                      WAITV(8); }                                            \
    else            { WAITV(0); }                                            \
    __builtin_amdgcn_sched_barrier(0);                                       \
    __builtin_amdgcn_s_barrier();                                            \
    __builtin_amdgcn_s_setprio(1);                                           \
    { CG_FRAGS(bufc, 0) MFMA_OP }                                            \
    { CG_FRAGS(bufc, 1) MFMA_OP }                                            \
    __builtin_amdgcn_s_setprio(0);                                           \
    __builtin_amdgcn_sched_barrier(0);                                       \
    __builtin_amdgcn_s_barrier();                                            \
  }

// --- A2 = A@A  (BNEG0, bf16 out) -------------------------------------------
__global__ __launch_bounds__(TPB) void cgemm_a2_k(
    const u16* __restrict__ Apr, const u16* __restrict__ Api,
    u16* __restrict__ Cr16, u16* __restrict__ Ci16)
{
  int flat = swz8(blockIdx.x, 256);
  int bm = (flat >> 4) * 64, bn = (flat & 15) * 64;
  CG_PRELUDE
  CG_PIPELINE(CG_MFMA_BNEG0, Apr, Api, Apr, Api)
  #pragma unroll
  for (int mf = 0; mf < 2; ++mf)
    #pragma unroll
    for (int nf = 0; nf < 2; ++nf) {
      int col = bn + wc * 32 + nf * 16 + (lane & 15);
      #pragma unroll
      for (int r = 0; r < 4; ++r) {
        int rowg = bm + wr * 32 + mf * 16 + (lane >> 4) * 4 + r;
        size_t o = (size_t)rowg * 1024 + col;
        Cr16[o] = f2bf(accR[mf][nf][r]);
        Ci16[o] = f2bf(accI[mf][nf][r]);
      }
    }
}

// --- batched: z=0: A4 = A2@A2 ; z=1: T1 = N@A2 + N   (BNEG1, bf16 out) -----
__global__ __launch_bounds__(TPB) void cgemm_pair_k(
    const u16* __restrict__ A2r, const u16* __restrict__ A2i,
    const u16* __restrict__ Nr2, const u16* __restrict__ Ni2,
    u16* __restrict__ A4r, u16* __restrict__ A4i,
    u16* __restrict__ T1r, u16* __restrict__ T1i)
{
  int flat = swz8(blockIdx.x, 512);
  int z = flat >> 8;
  int t8 = flat & 255;
  int bm = (t8 >> 4) * 64, bn = (t8 & 15) * 64;
  const u16* Apr = z ? Nr2 : A2r;
  const u16* Api = z ? Ni2 : A2i;
  u16* Cr16 = z ? T1r : A4r;
  u16* Ci16 = z ? T1i : A4i;
  CG_PRELUDE
  CG_PIPELINE(CG_MFMA_BNEG1, Apr, Api, A2r, A2i)
  #pragma unroll
  for (int mf = 0; mf < 2; ++mf)
    #pragma unroll
    for (int nf = 0; nf < 2; ++nf) {
      int col = bn + wc * 32 + nf * 16 + (lane & 15);
      #pragma unroll
      for (int r = 0; r < 4; ++r) {
        int rowg = bm + wr * 32 + mf * 16 + (lane >> 4) * 4 + r;
        size_t o = (size_t)rowg * 1024 + col;
        float vr = accR[mf][nf][r], vi = accI[mf][nf][r];
        if (z) { vr += bf2f(Nr2[o]); vi += bf2f(Ni2[o]); }   // +N
        Cr16[o] = f2bf(vr);
        Ci16[o] = f2bf(vi);
      }
    }
}

// --- V = 2*(T1@A4) + 2*T1 - I   (BNEG1, f32 out) ---------------------------
__global__ __launch_bounds__(TPB) void cgemm_v_k(
    const u16* __restrict__ T1r, const u16* __restrict__ T1i,
    const u16* __restrict__ A4r, const u16* __restrict__ A4i,
    float* __restrict__ Vr, float* __restrict__ Vi)
{
  int flat = swz8(blockIdx.x, 256);
  int bm = (flat >> 4) * 64, bn = (flat & 15) * 64;
  CG_PRELUDE
  CG_PIPELINE(CG_MFMA_BNEG1, T1r, T1i, A4r, A4i)
  #pragma unroll
  for (int mf = 0; mf < 2; ++mf)
    #pragma unroll
    for (int nf = 0; nf < 2; ++nf) {
      int col = bn + wc * 32 + nf * 16 + (lane & 15);
      #pragma unroll
      for (int r = 0; r < 4; ++r) {
        int rowg = bm + wr * 32 + mf * 16 + (lane >> 4) * 4 + r;
        size_t o = (size_t)rowg * 1024 + col;
        float dg = (rowg == col) ? 1.0f : 0.0f;
        Vr[o] = 2.0f * accR[mf][nf][r] + 2.0f * bf2f(T1r[o]) - dg;
        Vi[o] = 2.0f * accI[mf][nf][r] + 2.0f * bf2f(T1i[o]);
      }
    }
}

// ---------------------------------------------------------------------------
// Mt[d][k] = bf16( V[k][d]*exp(ls[d])*(1-alpha) + F[k][d]*alpha/32 )
// ---------------------------------------------------------------------------
__global__ __launch_bounds__(TPB) void build_mt_k(
    const float* __restrict__ Vr, const float* __restrict__ Vi,
    const float* __restrict__ log_sigma, const float* __restrict__ dft_weight,
    u16* __restrict__ Mtr, u16* __restrict__ Mti)
{
  __shared__ float Tr[64][65], Ti[64][65];
  int tid = threadIdx.x;
  int k0 = blockIdx.x * 64, d0 = blockIdx.y * 64;
  int c = tid & 63, r4 = tid >> 6;
  for (int p = 0; p < 16; ++p) {
    int r = r4 + p * 4;                       // local k index
    Tr[r][c] = Vr[(size_t)(k0 + r) * 1024 + d0 + c];
    Ti[r][c] = Vi[(size_t)(k0 + r) * 1024 + d0 + c];
  }
  __syncthreads();
  float alpha = sigmoidf_(dft_weight[0]);
  const float isq = 0.03125f * alpha;
  for (int p = 0; p < 16; ++p) {
    int dl = r4 + p * 4;                      // local d index (output row)
    int d = d0 + dl, k = k0 + c;
    float w1 = expf(log_sigma[d]) * (1.0f - alpha);
    int mm = (k * d) & 1023;
    float ang = -6.283185307179586f * (float)mm * (1.0f / 1024.0f);
    float sn, cs;
    sincosf(ang, &sn, &cs);
    size_t o = (size_t)d * 1024 + k;
    Mtr[o] = f2bf(Tr[c][dl] * w1 + cs * isq);
    Mti[o] = f2bf(Ti[c][dl] * w1 + sn * isq);
  }
}

// ---------------------------------------------------------------------------
// X f32 -> bf16 plane (vectorized, once)
// ---------------------------------------------------------------------------
__global__ __launch_bounds__(TPB) void xconv_k(
    const float* __restrict__ X, u16* __restrict__ Xb)
{
  int idx = (blockIdx.x * TPB + threadIdx.x) << 3;    // 8 per thread
  float4 a = *(const float4*)(X + idx);
  float4 b = *(const float4*)(X + idx + 4);
  u16 tmp[8];
  pack8(a, b, tmp);
  *(bf8v*)(Xb + idx) = *(bf8v*)tmp;
}

// ---------------------------------------------------------------------------
// per-d constants: op_decay, op_forcing, base_var
// ---------------------------------------------------------------------------
__global__ __launch_bounds__(TPB) void prep_k(
    const float* __restrict__ ld, const float* __restrict__ lf,
    const float* __restrict__ law_re, const float* __restrict__ law_im,
    const float* __restrict__ dt, const float* __restrict__ base_noise,
    float* __restrict__ od_re, float* __restrict__ od_im,
    float* __restrict__ of_re, float* __restrict__ of_im,
    float* __restrict__ bvar)
{
  int d = blockIdx.x * TPB + threadIdx.x;
  float dtr = dt[0];                              // DT_REF = 1.0
  float lre = tanhf(-expf(ld[d]) + law_re[d]) * 0.3f;
  float lim = lf[d] + law_im[d];
  float er = expf(lre * dtr);
  float sn, cs;
  sincosf(lim * dtr, &sn, &cs);
  float odr = er * cs, odi = er * sn;
  od_re[d] = odr;  od_im[d] = odi;
  float numr = odr - 1.0f, numi = odi;
  float denr = lre + 1e-8f, deni = lim;
  float inv = 1.0f / (denr * denr + deni * deni);
  of_re[d] = (numr * denr + numi * deni) * inv;
  of_im[d] = (numi * denr - numr * deni) * inv;
  float bn = base_noise[0];
  float bv = bn * bn * expm1f(2.0f * lre * dtr) / (2.0f * lre + 1e-8f);
  bvar[d] = fmaxf(bv, 0.0f);
}

// ---------------------------------------------------------------------------
// Wu1, Wu2 f32 -> bf16 planes
// ---------------------------------------------------------------------------
__global__ __launch_bounds__(TPB) void conv_w_k(
    const float* __restrict__ Wu1, const float* __restrict__ Wu2,
    u16* __restrict__ Wu1b, u16* __restrict__ Wu2b)
{
  int idx = blockIdx.x * TPB + threadIdx.x;     // 2 * 262144
  if (idx < 262144) Wu1b[idx] = f2bf(Wu1[idx]);
  else              Wu2b[idx - 262144] = f2bf(Wu2[idx - 262144]);
}

// ---------------------------------------------------------------------------
// M=16 split-K MFMA GEMM (partials) ; reduce adds bias (+sigmoid)
// ---------------------------------------------------------------------------
__global__ __launch_bounds__(TPB) void sgemm16_k(
    const float* __restrict__ A0, const float* __restrict__ A1,
    const float* __restrict__ Bw, float* __restrict__ Pp, int N)
{
  __shared__ __align__(16) u16 lds[2 * BUF1];
  int tid = threadIdx.x;
  int c0 = blockIdx.x * 64;
  int kbase = blockIdx.y * 256;
  int lane = tid & 63;
  int w = tid >> 6;
  int row = tid >> 2, kq = (tid & 3) << 3;

  f32x4 acc = {};
  float4 pb0, pb1;

  auto gload = [&](int k0) {
    const float* p = Bw + (size_t)(c0 + row) * 2048 + k0 + kq;
    pb0 = *(const float4*)p; pb1 = *(const float4*)(p + 4);
  };
  auto stolds = [&](int buf) {
    pack8(pb0, pb1, lds + buf * BUF1 + row * LSTR + kq);
  };
  auto compute = [&](int buf, int k0) {
    int ar = lane & 15;
    int ko = (lane >> 4) * 8;
    const float* ap = (k0 < 1024) ? (A0 + (size_t)ar * 1024 + k0 + ko)
                                  : (A1 + (size_t)ar * 1024 + k0 + ko - 1024);
    float4 a0 = *(const float4*)ap, a1 = *(const float4*)(ap + 4);
    u16 abuf[8];
    pack8(a0, a1, abuf);
    bf8v af = *(bf8v*)abuf;
    const u16* L = lds + buf * BUF1;
    bf8v bfr = *(const bf8v*)(L + (w * 16 + (lane & 15)) * LSTR + ko);
    acc = __builtin_amdgcn_mfma_f32_16x16x32_bf16(af, bfr, acc, 0, 0, 0);
  };

  gload(kbase); stolds(0); __syncthreads();
  int cur = 0;
  for (int t = 0; t < 8; ++t) {
    int k0 = kbase + t * 32;
    if (t < 7) gload(k0 + 32);
    compute(cur, k0);
    if (t < 7) stolds(cur ^ 1);
    __syncthreads();
    cur ^= 1;
  }

  int c = c0 + w * 16 + (lane & 15);
  #pragma unroll
  for (int r = 0; r < 4; ++r) {
    int rr = (lane >> 4) * 4 + r;
    Pp[((size_t)blockIdx.y * 16 + rr) * N + c] = acc[r];
  }
}

__global__ __launch_bounds__(TPB) void red16_k(
    const float* __restrict__ Pp, const float* __restrict__ bias,
    float* __restrict__ out, int N, int act)
{
  int idx = blockIdx.x * TPB + threadIdx.x;   // 16*N
  int c = idx & (N - 1);
  float v = bias[c];
  #pragma unroll
  for (int s = 0; s < 8; ++s) v += Pp[(size_t)s * 16 * N + idx];
  if (act == 1) v = sigmoidf_(v);
  out[idx] = v;
}

// ---------------------------------------------------------------------------
// flux_next = flux*fdecay + update ; FN planes + f32 output 1 = Re(flux_next)
// ---------------------------------------------------------------------------
__global__ __launch_bounds__(TPB) void flux_k(
    const float* __restrict__ xin,
    const float* __restrict__ flux_re, const float* __restrict__ flux_im,
    const float* __restrict__ decay_re, const float* __restrict__ decay_im,
    float* __restrict__ FNr, float* __restrict__ FNi,
    float* __restrict__ out1)
{
  int idx = blockIdx.x * TPB + threadIdx.x;     // 16 * 1024
  int b = idx >> 10, d = idx & 1023;
  float fdr = sigmoidf_(decay_re[d]);
  float fdi = decay_im[d];
  float fr = flux_re[idx], fi = flux_im[idx];
  float ur = xin[b * 2048 + d], ui = xin[b * 2048 + 1024 + d];
  float nr = fr * fdr - fi * fdi + ur;
  float ni = fr * fdi + fi * fdr + ui;
  FNr[idx] = nr;  FNi[idx] = ni;
  out1[idx] = nr;                                // f32, real part only
}

// ---------------------------------------------------------------------------
// x_tilde = Xb @ M + h_next epilogue -> Hrb bf16 (BK=64, 2-buffer pipeline)
// ---------------------------------------------------------------------------
__global__ __launch_bounds__(TPB) void xmh_nt_k(
    const u16* __restrict__ Xb,
    const u16* __restrict__ Mtr, const u16* __restrict__ Mti,
    const float* __restrict__ gate, const float* __restrict__ proj,
    const float* __restrict__ od_re, const float* __restrict__ od_im,
    const float* __restrict__ of_re, const float* __restrict__ of_im,
    const float* __restrict__ hp_re, const float* __restrict__ hp_im,
    u16* __restrict__ Hrb)
{
  __shared__ __align__(16) u16 lds[2 * 3 * PSZ2];     // 48KB
  int flat = swz8(blockIdx.x, 1024);
  int bm = (flat >> 4) * 64, bn = (flat & 15) * 64;
  int tid = threadIdx.x;
  int lane = tid & 63;
  int wr = (tid >> 7) & 1, wc = (tid >> 6) & 1;
  int lr8_ = ((tid & 63) >> 3) + ((tid >> 6) << 4);
  int ks2_ = (((lane & 7) ^ (lane >> 3)) << 3);
  u16* Lw_ = lds + ((tid >> 6) << 10);

  f32x4 accR[2][2] = {};
  f32x4 accI[2][2] = {};

#define XM_STAGE(buf, k0)                                                    \
  { u16* Lb = Lw_ + (buf) * (3 * PSZ2);                                      \
    gload16(Xb  + (size_t)(bm + lr8_) * 1024 + (k0) + ks2_,     Lb + 0 * PSZ2);       \
    gload16(Xb  + (size_t)(bm + lr8_ + 8) * 1024 + (k0) + ks2_, Lb + 0 * PSZ2 + 512); \
    gload16(Mtr + (size_t)(bn + lr8_) * 1024 + (k0) + ks2_,     Lb + 1 * PSZ2);       \
    gload16(Mtr + (size_t)(bn + lr8_ + 8) * 1024 + (k0) + ks2_, Lb + 1 * PSZ2 + 512); \
    gload16(Mti + (size_t)(bn + lr8_) * 1024 + (k0) + ks2_,     Lb + 2 * PSZ2);       \
    gload16(Mti + (size_t)(bn + lr8_ + 8) * 1024 + (k0) + ks2_, Lb + 2 * PSZ2 + 512); }
#define XM_COMPUTE(buf, s)                                                   \
  { const u16* L = lds + (buf) * (3 * PSZ2);                                 \
    int rA = wr * 32 + (lane & 15);                                          \
    int rB = wc * 32 + (lane & 15);                                          \
    int kq = lane >> 4;                                                      \
    bf8v a[2], br[2], bi[2];                                                 \
    a[0]  = fragld2(L + 0 * PSZ2, rA, kq, s);  a[1]  = fragld2(L + 0 * PSZ2, rA + 16, kq, s); \
    br[0] = fragld2(L + 1 * PSZ2, rB, kq, s);  br[1] = fragld2(L + 1 * PSZ2, rB + 16, kq, s); \
    bi[0] = fragld2(L + 2 * PSZ2, rB, kq, s);  bi[1] = fragld2(L + 2 * PSZ2, rB + 16, kq, s); \
    _Pragma("unroll")                                                        \
    for (int mf = 0; mf < 2; ++mf)                                           \
      _Pragma("unroll")                                                      \
      for (int nf = 0; nf < 2; ++nf) {                                       \
        accR[mf][nf] = __builtin_amdgcn_mfma_f32_16x16x32_bf16(a[mf], br[nf], accR[mf][nf], 0, 0, 0); \
        accI[mf][nf] = __builtin_amdgcn_mfma_f32_16x16x32_bf16(a[mf], bi[nf], accI[mf][nf], 0, 0, 0); \
      } }

  XM_STAGE(0, 0);
  #pragma unroll 1
  for (int t = 0; t < 16; ++t) {
    int bufc = t & 1;
    if (t + 1 < 16) { XM_STAGE(bufc ^ 1, (t + 1) * 64); WAITV(6); }
    else            { WAITV(0); }
    __builtin_amdgcn_sched_barrier(0);
    __builtin_amdgcn_s_barrier();
    __builtin_amdgcn_s_setprio(1);
    XM_COMPUTE(bufc, 0)
    XM_COMPUTE(bufc, 1)
    __builtin_amdgcn_s_setprio(0);
    __builtin_amdgcn_sched_barrier(0);
    __builtin_amdgcn_s_barrier();
  }

  #pragma unroll
  for (int mf = 0; mf < 2; ++mf)
    #pragma unroll
    for (int nf = 0; nf < 2; ++nf) {
      int c = bn + wc * 32 + nf * 16 + (lane & 15);
      #pragma unroll
      for (int r = 0; r < 4; ++r) {
        int t = bm + wr * 32 + mf * 16 + (lane >> 4) * 4 + r;
        int b = t >> 8;                         // 64-row tile never straddles batch
        float g  = gate[b * 1024 + c];
        float sr = proj[b * 2048 + c];
        float si = proj[b * 2048 + 1024 + c];
        float fr = accR[mf][nf][r] * g + sr * (1.0f - g);
        float fi = accI[mf][nf][r] * g + si * (1.0f - g);
        float odr = od_re[c], odi = od_im[c];
        float ofr = of_re[c], ofi = of_im[c];
        size_t off = (size_t)t * 1024 + c;
        float pr = hp_re[off], pi = hp_im[off];
        Hrb[off] = f2bf(pr * odr - pi * odi + fr * ofr - fi * ofi);
      }
    }
}

// ---------------------------------------------------------------------------
// real NT GEMM, bf16: C = A@B^T.  KI = K/32.  3-buffer counted-vmcnt, BK=32.
// EPI=0 (mlp1): silu->bf16 direct.  EPI=2 (u): softplus->bf16 via LDS tile.
// ---------------------------------------------------------------------------
template<int KI, int EPI>
__global__ __launch_bounds__(TPB) void rgemm_nt_k(
    const u16* __restrict__ A, const u16* __restrict__ B,
    const float* __restrict__ bias,
    u16* __restrict__ C16, int nbxl, int total)
{
  __shared__ __align__(16) u16 lds[3 * 2 * PSZ];   // 24KB (ct needs 17.4KB)
  const int K = KI * 32;
  int tid = threadIdx.x;
  int flat = swz8(blockIdx.x, total);
  int bm = (flat >> nbxl) * 64;
  int bn = (flat & ((1 << nbxl) - 1)) * 64;
  const int N = 64 << nbxl;
  int lane = tid & 63;
  int wr = (tid >> 7) & 1, wc = (tid >> 6) & 1;
  int lr_ = ((tid & 63) >> 2) + ((tid >> 6) << 4);
  int ks_ = (((tid & 3) ^ ((tid >> 3) & 3)) << 3);
  u16* Lw_ = lds + ((tid >> 6) << 9);

  f32x4 acc[2][2] = {};

#define RG_STAGE(buf, k0)                                                    \
  { u16* Lb = Lw_ + (buf) * (2 * PSZ);                                       \
    gload16(A + (size_t)(bm + lr_) * K + (k0) + ks_, Lb + 0 * PSZ);          \
    gload16(B + (size_t)(bn + lr_) * K + (k0) + ks_, Lb + 1 * PSZ); }
#define RG_COMPUTE(buf)                                                      \
  { const u16* L = lds + (buf) * (2 * PSZ);                                  \
    int rA = wr * 32 + (lane & 15);                                          \
    int rB = wc * 32 + (lane & 15);                                          \
    int kq = lane >> 4;                                                      \
    bf8v a[2], b[2];                                                         \
    a[0] = fragld(L + 0 * PSZ, rA, kq);  a[1] = fragld(L + 0 * PSZ, rA + 16, kq); \
    b[0] = fragld(L + 1 * PSZ, rB, kq);  b[1] = fragld(L + 1 * PSZ, rB + 16, kq); \
    _Pragma("unroll")                                                        \
    for (int mf = 0; mf < 2; ++mf)                                           \
      _Pragma("unroll")                                                      \
      for (int nf = 0; nf < 2; ++nf)                                         \
        acc[mf][nf] = __builtin_amdgcn_mfma_f32_16x16x32_bf16(a[mf], b[nf], acc[mf][nf], 0, 0, 0); }

  RG_STAGE(0, 0);
  RG_STAGE(1, 32);
  #pragma unroll 1
  for (int t = 0; t < KI; ++t) {
    int bufc = t % 3;
    if (t + 2 < KI) { RG_STAGE((t + 2) % 3, (t + 2) * 32); }
    if (t + 2 < KI)      { WAITV(4); }
    else if (t + 1 < KI) { WAITV(2); }
    else                 { WAITV(0); }
    __builtin_amdgcn_sched_barrier(0);
    __builtin_amdgcn_s_barrier();
    __builtin_amdgcn_s_setprio(1);
    RG_COMPUTE(bufc)
    __builtin_amdgcn_s_setprio(0);
    __builtin_amdgcn_sched_barrier(0);
    __builtin_amdgcn_s_barrier();
  }

  if constexpr (EPI == 0) {
    #pragma unroll
    for (int mf = 0; mf < 2; ++mf)
      #pragma unroll
      for (int nf = 0; nf < 2; ++nf) {
        int c = bn + wc * 32 + nf * 16 + (lane & 15);
        #pragma unroll
        for (int r = 0; r < 4; ++r) {
          int t = bm + wr * 32 + mf * 16 + (lane >> 4) * 4 + r;
          float v = acc[mf][nf][r] + bias[c];
          v = v * sigmoidf_(v);                       // silu (fast exp)
          C16[(size_t)t * N + c] = f2bf(v);
        }
      }
  } else {
    // acc -> LDS f32 tile, then row-contiguous packed-bf16 softplus stores
    float* ct = (float*)lds;
    __syncthreads();
    #pragma unroll
    for (int mf = 0; mf < 2; ++mf)
      #pragma unroll
      for (int nf = 0; nf < 2; ++nf) {
        int rbase = wr * 32 + mf * 16 + (lane >> 4) * 4;
        int cc = wc * 32 + nf * 16 + (lane & 15);
        #pragma unroll
        for (int r = 0; r < 4; ++r)
          ct[(rbase + r) * CSTR + cc] = acc[mf][nf][r];
      }
    __syncthreads();
    int w = tid >> 6, l = tid & 63;
    int lcol = (l & 15) * 4;
    #pragma unroll
    for (int p = 0; p < 4; ++p) {
      int lrow = w * 16 + p * 4 + (l >> 4);
      int t = bm + lrow;
      int c = bn + lcol;
      float4 v4 = *(float4*)&ct[lrow * CSTR + lcol];
      float4 bi4 = *(const float4*)(bias + c);
      float u0 = spf_(v4.x + bi4.x);
      float u1 = spf_(v4.y + bi4.y);
      float u2 = spf_(v4.z + bi4.z);
      float u3 = spf_(v4.w + bi4.w);
      *(uint2*)(C16 + (size_t)t * N + c) = packbf4(u0, u1, u2, u3);
    }
  }
}

// ---------------------------------------------------------------------------
// out0 = Hrb + nre * sqrt(bvar * u) * sqrt(0.5)   (pure elementwise, x8)
// ---------------------------------------------------------------------------
__global__ __launch_bounds__(TPB) void fin_k(
    const u16* __restrict__ Hrb, const u16* __restrict__ ub,
    const float* __restrict__ nre, const float* __restrict__ bvar,
    float* __restrict__ out0)
{
  int idx = (blockIdx.x * TPB + threadIdx.x) << 3;    // 8 per thread
  int c = idx & 1023;
  bf8v hb = *(const bf8v*)(Hrb + idx);
  bf8v uv = *(const bf8v*)(ub + idx);
  float4 n0 = *(const float4*)(nre + idx);
  float4 n1 = *(const float4*)(nre + idx + 4);
  float4 b0 = *(const float4*)(bvar + c);
  float4 b1 = *(const float4*)(bvar + c + 4);
  float4 o0, o1;
  const float s2 = 0.7071067811865476f;
  #pragma unroll
  for (int j = 0; j < 4; ++j) {
    float sc = sqrtf(((const float*)&b0)[j] * bf2f((u16)uv[j])) * s2;
    ((float*)&o0)[j] = bf2f((u16)hb[j]) + ((const float*)&n0)[j] * sc;
  }
  #pragma unroll
  for (int j = 0; j < 4; ++j) {
    float sc = sqrtf(((const float*)&b1)[j] * bf2f((u16)uv[4 + j])) * s2;
    ((float*)&o1)[j] = bf2f((u16)hb[4 + j]) + ((const float*)&n1)[j] * sc;
  }
  *(float4*)(out0 + idx)     = o0;
  *(float4*)(out0 + idx + 4) = o1;
}

// ---------------------------------------------------------------------------
extern "C" void kernel_launch(void* const* d_in, const int* in_sizes, int n_in,
                              void* d_out, int out_size, void* d_ws, size_t ws_size,
                              hipStream_t stream) {
  (void)in_sizes; (void)n_in; (void)out_size;

  const float* x_input    = (const float*)d_in[0];
  const float* h_prev_re  = (const float*)d_in[1];
  const float* h_prev_im  = (const float*)d_in[2];
  const float* xg_re      = (const float*)d_in[3];
  const float* xg_im      = (const float*)d_in[4];
  const float* flux_re    = (const float*)d_in[5];
  const float* flux_im    = (const float*)d_in[6];
  const float* dt         = (const float*)d_in[7];
  const float* v_raw_re   = (const float*)d_in[10];
  const float* v_raw_im   = (const float*)d_in[11];
  const float* log_sigma  = (const float*)d_in[12];
  const float* dft_weight = (const float*)d_in[13];
  const float* decay_re   = (const float*)d_in[14];
  const float* decay_im   = (const float*)d_in[15];
  const float* Wi_in      = (const float*)d_in[16];
  const float* bi         = (const float*)d_in[17];
  const float* Wo         = (const float*)d_in[18];
  const float* bo         = (const float*)d_in[19];
  const float* Wg         = (const float*)d_in[20];
  const float* bg         = (const float*)d_in[21];
  const float* ld         = (const float*)d_in[22];
  const float* lf         = (const float*)d_in[23];
  const float* law_re     = (const float*)d_in[24];
  const float* law_im     = (const float*)d_in[25];
  const float* base_noise = (const float*)d_in[26];
  const float* Wu1        = (const float*)d_in[27];
  const float* bu1        = (const float*)d_in[28];
  const float* Wu2        = (const float*)d_in[29];
  const float* bu2        = (const float*)d_in[30];
  const float* noise_re   = (const float*)d_in[31];

  // --- workspace: 16 bf16-sized planes (2MB each) = 32MB --------------------
  const size_t PL16 = 1024ull * 1024ull;        // u16 per plane
  if (ws_size < 16 * PL16 * 2) return;          // too small -> zeros (diagnostic)

  u16* P = (u16*)d_ws;
  u16* Ar  = P + 0 * PL16;   u16* Ai  = P + 1 * PL16;   // A       (dead after A2)
  u16* Nr  = P + 2 * PL16;   u16* Ni  = P + 3 * PL16;   // N = I-A (dead after pair)
  u16* A2r = P + 4 * PL16;   u16* A2i = P + 5 * PL16;   // dead after pair
  u16* A4r = P + 6 * PL16;   u16* A4i = P + 7 * PL16;   // dead after V
  u16* T1r = P + 8 * PL16;   u16* T1i = P + 9 * PL16;   // dead after V
  // liveness reuse (stream-ordered):
  float* Vr = (float*)(P + 0 * PL16);   // 8MB over P0..P3 (A,N dead)
  float* Vi = (float*)(P + 2 * PL16);
  u16* Mtr  = P + 8 * PL16;             // over T1 (dead after V)
  u16* Mti  = P + 9 * PL16;
  u16* Xb   = P + 4 * PL16;             // 8MB over A2,A4 (dead after V)
  float* Pp = (float*)(P + 0 * PL16);   // 1MB split-K partials (V dead after build_mt)
  u16* ub   = P + 0 * PL16;             // 8MB u-plane (Pp dead after red16 chain)
  u16* Hrb  = P + 10 * PL16;            // 8MB, P10..P13
  u16* mlp1b = P + 14 * PL16;           // 4096x256
  u16* Wu1b  = P + 15 * PL16;           // 262144 u16
  u16* Wu2b  = Wu1b + 262144;
  float* sm  = (float*)(P + 15 * PL16 + 524288);
  float* xin  = sm;                     // 16x2048
  float* proj = xin + 32768;            // 16x2048
  float* FNr  = proj + 32768;           // 16x1024
  float* FNi  = FNr + 16384;
  float* gate = FNi + 16384;            // 16x1024
  float* od_re = gate + 16384;
  float* od_im = od_re + 1024;
  float* of_re = od_im + 1024;
  float* of_im = of_re + 1024;
  float* bvar  = of_im + 1024;

  float* out0f = (float*)d_out;                       // 4096x1024 f32 (real)
  float* out1f = out0f + (size_t)4096 * 1024;         // 16x1024 f32 (real)

  // --- Cayley: V = 2*(I-A)(I+A^2)(I+A^4) - I, err <= 2.2e-3 -----------------
  build_a_k<<<4096, TPB, 0, stream>>>(v_raw_re, v_raw_im, Ar, Ai, Nr, Ni);
  cgemm_a2_k<<<256, TPB, 0, stream>>>(Ar, Ai, A2r, A2i);                 // A2 = A@A
  cgemm_pair_k<<<512, TPB, 0, stream>>>(A2r, A2i, Nr, Ni,                // A4 = A2@A2
                                        A4r, A4i, T1r, T1i);             // T1 = N@A2+N
  cgemm_v_k<<<256, TPB, 0, stream>>>(T1r, T1i, A4r, A4i, Vr, Vi);        // V
  build_mt_k<<<dim3(16, 16), TPB, 0, stream>>>(Vr, Vi, log_sigma, dft_weight, Mtr, Mti);
  xconv_k<<<2048, TPB, 0, stream>>>(x_input, Xb);

  // --- per-d constants + weight conversion ----------------------------------
  prep_k<<<4, TPB, 0, stream>>>(ld, lf, law_re, law_im, dt, base_noise,
                                od_re, od_im, of_re, of_im, bvar);
  conv_w_k<<<2048, TPB, 0, stream>>>(Wu1, Wu2, Wu1b, Wu2b);

  // --- B=16 chain: split-K MFMA gemms ---------------------------------------
  sgemm16_k<<<dim3(32, 8), TPB, 0, stream>>>(xg_re, xg_im, Wi_in, Pp, 2048);
  red16_k<<<128, TPB, 0, stream>>>(Pp, bi, xin, 2048, 0);
  flux_k<<<64, TPB, 0, stream>>>(xin, flux_re, flux_im, decay_re, decay_im,
                                 FNr, FNi, out1f);
  sgemm16_k<<<dim3(32, 8), TPB, 0, stream>>>(FNr, FNi, Wo, Pp, 2048);
  red16_k<<<128, TPB, 0, stream>>>(Pp, bo, proj, 2048, 0);
  sgemm16_k<<<dim3(16, 8), TPB, 0, stream>>>(FNr, FNi, Wg, Pp, 1024);
  red16_k<<<64, TPB, 0, stream>>>(Pp, bg, gate, 1024, 1);

  // --- x_tilde = Xb@M fused with h_next epilogue -> Hrb bf16 ----------------
  xmh_nt_k<<<1024, TPB, 0, stream>>>(Xb, Mtr, Mti, gate, proj,
                                     od_re, od_im, of_re, of_im,
                                     h_prev_re, h_prev_im, Hrb);

  // --- u-MLP (MFMA) + elementwise final -------------------------------------
  rgemm_nt_k<32, 0><<<256, TPB, 0, stream>>>(Hrb, Wu1b, bu1, mlp1b, 2, 256);
  rgemm_nt_k<8, 2><<<1024, TPB, 0, stream>>>(mlp1b, Wu2b, bu2, ub, 4, 1024);
  fin_k<<<2048, TPB, 0, stream>>>(Hrb, ub, noise_re, bvar, out0f);
}

// Round 18
// 172.053 us; speedup vs baseline: 1.0672x; 1.0322x over previous
//
#include <hip/hip_runtime.h>
#include <cstddef>

#define TPB 256

typedef short bf8v  __attribute__((ext_vector_type(8)));   // 8 bf16 bit-patterns
typedef float f32x4 __attribute__((ext_vector_type(4)));
typedef unsigned short u16;

#define PSZ 2048     // u16 per LDS plane [64][32] (rgemm staging)
#define PSZ2 4096    // u16 per LDS plane [64][64] (BK=64 staging)
#define LSTR 40      // legacy stride for sgemm16 staging
#define BUF1 2560
#define CSTR 68      // f32 LDS epilogue-tile row stride

static __device__ __forceinline__ u16 f2bf(float x) {
  unsigned int u = __float_as_uint(x);
  u = (u + 0x7FFFu + ((u >> 16) & 1u)) >> 16;   // RNE f32 -> bf16
  return (u16)u;
}
static __device__ __forceinline__ float bf2f(u16 x) {
  return __uint_as_float(((unsigned int)x) << 16);
}
static __device__ __forceinline__ float sigmoidf_(float x) {
  return 1.0f / (1.0f + __expf(-x));            // fast exp (v_exp_f32)
}
static __device__ __forceinline__ float spf_(float v) {   // fast softplus
  return (v > 15.0f) ? v : __logf(1.0f + __expf(v));
}
static __device__ __forceinline__ bf8v neg8(bf8v a) {
  #pragma unroll
  for (int i = 0; i < 8; ++i) a[i] ^= (short)0x8000;
  return a;
}
static __device__ __forceinline__ void pack8(const float4& x, const float4& y,
                                             u16* dst) {
  unsigned int* d = (unsigned int*)dst;
  d[0] = ((unsigned)f2bf(x.y) << 16) | f2bf(x.x);
  d[1] = ((unsigned)f2bf(x.w) << 16) | f2bf(x.z);
  d[2] = ((unsigned)f2bf(y.y) << 16) | f2bf(y.x);
  d[3] = ((unsigned)f2bf(y.w) << 16) | f2bf(y.z);
}
static __device__ __forceinline__ uint2 packbf4(float a, float b, float c, float d) {
  uint2 r;
  r.x = ((unsigned)f2bf(b) << 16) | f2bf(a);
  r.y = ((unsigned)f2bf(d) << 16) | f2bf(c);
  return r;
}
// async global->LDS, 16B per lane; LDS dest is wave-uniform base + lane*16
static __device__ __forceinline__ void gload16(const u16* g, u16* l) {
  __builtin_amdgcn_global_load_lds((const __attribute__((address_space(1))) void*)g,
                                   (__attribute__((address_space(3))) void*)l,
                                   16, 0, 0);
}
// BK=32 fragment read with k-chunk XOR swizzle (rgemm path)
static __device__ __forceinline__ bf8v fragld(const u16* plane, int r, int kq) {
  int kb = (kq << 4) ^ (((r >> 1) & 3) << 4);
  return *(const bf8v*)(plane + r * 32 + (kb >> 1));
}
// BK=64 fragment read: global chunk (s*4+kq) at row r lives at chunk^(r&7)
static __device__ __forceinline__ bf8v fragld2(const u16* plane, int r, int kq, int s) {
  int ch = ((s << 2) + kq) ^ (r & 7);
  return *(const bf8v*)(plane + r * 64 + (ch << 3));
}
// XCD-aware bijective block swizzle (T % 8 == 0)
static __device__ __forceinline__ int swz8(int flat, int T) {
  return (flat & 7) * (T >> 3) + (flat >> 3);
}

#define WAITV(n) asm volatile("s_waitcnt vmcnt(" #n ")" ::: "memory")

// ---------------------------------------------------------------------------
// A = (v - v^T)re + i(v + v^T)im ; N = I - A   -> bf16 planes
// ---------------------------------------------------------------------------
__global__ __launch_bounds__(TPB) void build_a_k(
    const float* __restrict__ vre, const float* __restrict__ vim,
    u16* __restrict__ Ar, u16* __restrict__ Ai,
    u16* __restrict__ Nr, u16* __restrict__ Ni)
{
  int idx = blockIdx.x * TPB + threadIdx.x;
  int i = idx >> 10, j = idx & 1023;
  float ar = vre[idx] - vre[j * 1024 + i];
  float ai = vim[idx] + vim[j * 1024 + i];
  float dg = (i == j) ? 1.0f : 0.0f;
  Ar[idx] = f2bf(ar);       Ai[idx] = f2bf(ai);
  Nr[idx] = f2bf(dg - ar);  Ni[idx] = f2bf(-ai);
}

// ---------------------------------------------------------------------------
// complex-NT, BK=64, 2-buffer counted-vmcnt pipeline (16 phases, 32 MFMA each)
//   BNEG=0 (B-plane = A):     B_true = (-b^r, +b^i)
//   BNEG=1 (B-plane = A^2k):  B_true = (+b^r, -b^i)
// ---------------------------------------------------------------------------
#define CG_PRELUDE                                                           \
  __shared__ __align__(16) u16 lds[2 * 4 * PSZ2];       /* 64KB */           \
  int tid = threadIdx.x;                                                     \
  int lane = tid & 63;                                                       \
  int wr = (tid >> 7) & 1, wc = (tid >> 6) & 1;                              \
  int lr8_ = ((tid & 63) >> 3) + ((tid >> 6) << 4);     /* w*16 + lane>>3 */ \
  int ks2_ = (((lane & 7) ^ (lane >> 3)) << 3);                              \
  u16* Lw_ = lds + ((tid >> 6) << 10);                  /* w*16 rows * 64 */ \
  f32x4 accR[2][2] = {};                                                     \
  f32x4 accI[2][2] = {};

#define CG_STAGE(buf, k0, PAr, PAi, PBr, PBi)                                \
  { u16* Lb = Lw_ + (buf) * (4 * PSZ2);                                      \
    gload16((PAr) + (size_t)(bm + lr8_) * 1024 + (k0) + ks2_,     Lb + 0 * PSZ2);       \
    gload16((PAr) + (size_t)(bm + lr8_ + 8) * 1024 + (k0) + ks2_, Lb + 0 * PSZ2 + 512); \
    gload16((PAi) + (size_t)(bm + lr8_) * 1024 + (k0) + ks2_,     Lb + 1 * PSZ2);       \
    gload16((PAi) + (size_t)(bm + lr8_ + 8) * 1024 + (k0) + ks2_, Lb + 1 * PSZ2 + 512); \
    gload16((PBr) + (size_t)(bn + lr8_) * 1024 + (k0) + ks2_,     Lb + 2 * PSZ2);       \
    gload16((PBr) + (size_t)(bn + lr8_ + 8) * 1024 + (k0) + ks2_, Lb + 2 * PSZ2 + 512); \
    gload16((PBi) + (size_t)(bn + lr8_) * 1024 + (k0) + ks2_,     Lb + 3 * PSZ2);       \
    gload16((PBi) + (size_t)(bn + lr8_ + 8) * 1024 + (k0) + ks2_, Lb + 3 * PSZ2 + 512); }

#define CG_FRAGS(buf, s)                                                     \
  const u16* L = lds + (buf) * (4 * PSZ2);                                   \
  int rA = wr * 32 + (lane & 15);                                            \
  int rB = wc * 32 + (lane & 15);                                            \
  int kq = lane >> 4;                                                        \
  bf8v ar[2], ai[2], br[2], bi[2];                                           \
  ar[0] = fragld2(L + 0 * PSZ2, rA, kq, s);  ar[1] = fragld2(L + 0 * PSZ2, rA + 16, kq, s); \
  ai[0] = fragld2(L + 1 * PSZ2, rA, kq, s);  ai[1] = fragld2(L + 1 * PSZ2, rA + 16, kq, s); \
  br[0] = fragld2(L + 2 * PSZ2, rB, kq, s);  br[1] = fragld2(L + 2 * PSZ2, rB + 16, kq, s); \
  bi[0] = fragld2(L + 3 * PSZ2, rB, kq, s);  bi[1] = fragld2(L + 3 * PSZ2, rB + 16, kq, s);

#define CG_MFMA_BNEG0                                                        \
  { bf8v nbr[2] = { neg8(br[0]), neg8(br[1]) };                              \
    bf8v nbi[2] = { neg8(bi[0]), neg8(bi[1]) };                              \
    _Pragma("unroll")                                                        \
    for (int mf = 0; mf < 2; ++mf)                                           \
      _Pragma("unroll")                                                      \
      for (int nf = 0; nf < 2; ++nf) {                                       \
        accR[mf][nf] = __builtin_amdgcn_mfma_f32_16x16x32_bf16(ar[mf], nbr[nf], accR[mf][nf], 0, 0, 0); \
        accR[mf][nf] = __builtin_amdgcn_mfma_f32_16x16x32_bf16(ai[mf], nbi[nf], accR[mf][nf], 0, 0, 0); \
        accI[mf][nf] = __builtin_amdgcn_mfma_f32_16x16x32_bf16(ar[mf], bi[nf],  accI[mf][nf], 0, 0, 0); \
        accI[mf][nf] = __builtin_amdgcn_mfma_f32_16x16x32_bf16(ai[mf], nbr[nf], accI[mf][nf], 0, 0, 0); \
      } }

#define CG_MFMA_BNEG1                                                        \
  { bf8v nbi[2] = { neg8(bi[0]), neg8(bi[1]) };                              \
    _Pragma("unroll")                                                        \
    for (int mf = 0; mf < 2; ++mf)                                           \
      _Pragma("unroll")                                                      \
      for (int nf = 0; nf < 2; ++nf) {                                       \
        accR[mf][nf] = __builtin_amdgcn_mfma_f32_16x16x32_bf16(ar[mf], br[nf],  accR[mf][nf], 0, 0, 0); \
        accR[mf][nf] = __builtin_amdgcn_mfma_f32_16x16x32_bf16(ai[mf], bi[nf],  accR[mf][nf], 0, 0, 0); \
        accI[mf][nf] = __builtin_amdgcn_mfma_f32_16x16x32_bf16(ar[mf], nbi[nf], accI[mf][nf], 0, 0, 0); \
        accI[mf][nf] = __builtin_amdgcn_mfma_f32_16x16x32_bf16(ai[mf], br[nf],  accI[mf][nf], 0, 0, 0); \
      } }

#define CG_PIPELINE(MFMA_OP, PAr, PAi, PBr, PBi)                             \
  CG_STAGE(0, 0, PAr, PAi, PBr, PBi);                                        \
  _Pragma("unroll 1")                                                        \
  for (int t = 0; t < 16; ++t) {                                             \
    int bufc = t & 1;                                                        \
    if (t + 1 < 16) { CG_STAGE(bufc ^ 1, (t + 1) * 64, PAr, PAi, PBr, PBi);  \
                      WAITV(8); }                                            \
    else            { WAITV(0); }                                            \
    __builtin_amdgcn_sched_barrier(0);                                       \
    __builtin_amdgcn_s_barrier();                                            \
    __builtin_amdgcn_s_setprio(1);                                           \
    { CG_FRAGS(bufc, 0) MFMA_OP }                                            \
    { CG_FRAGS(bufc, 1) MFMA_OP }                                            \
    __builtin_amdgcn_s_setprio(0);                                           \
    __builtin_amdgcn_sched_barrier(0);                                       \
    __builtin_amdgcn_s_barrier();                                            \
  }

// --- A2 = A@A  (BNEG0, bf16 out) -------------------------------------------
__global__ __launch_bounds__(TPB) void cgemm_a2_k(
    const u16* __restrict__ Apr, const u16* __restrict__ Api,
    u16* __restrict__ Cr16, u16* __restrict__ Ci16)
{
  int flat = swz8(blockIdx.x, 256);
  int bm = (flat >> 4) * 64, bn = (flat & 15) * 64;
  CG_PRELUDE
  CG_PIPELINE(CG_MFMA_BNEG0, Apr, Api, Apr, Api)
  #pragma unroll
  for (int mf = 0; mf < 2; ++mf)
    #pragma unroll
    for (int nf = 0; nf < 2; ++nf) {
      int col = bn + wc * 32 + nf * 16 + (lane & 15);
      #pragma unroll
      for (int r = 0; r < 4; ++r) {
        int rowg = bm + wr * 32 + mf * 16 + (lane >> 4) * 4 + r;
        size_t o = (size_t)rowg * 1024 + col;
        Cr16[o] = f2bf(accR[mf][nf][r]);
        Ci16[o] = f2bf(accI[mf][nf][r]);
      }
    }
}

// --- batched: z=0: A4 = A2@A2 ; z=1: T1 = N@A2 + N   (BNEG1, bf16 out) -----
__global__ __launch_bounds__(TPB) void cgemm_pair_k(
    const u16* __restrict__ A2r, const u16* __restrict__ A2i,
    const u16* __restrict__ Nr2, const u16* __restrict__ Ni2,
    u16* __restrict__ A4r, u16* __restrict__ A4i,
    u16* __restrict__ T1r, u16* __restrict__ T1i)
{
  int flat = swz8(blockIdx.x, 512);
  int z = flat >> 8;
  int t8 = flat & 255;
  int bm = (t8 >> 4) * 64, bn = (t8 & 15) * 64;
  const u16* Apr = z ? Nr2 : A2r;
  const u16* Api = z ? Ni2 : A2i;
  u16* Cr16 = z ? T1r : A4r;
  u16* Ci16 = z ? T1i : A4i;
  CG_PRELUDE
  CG_PIPELINE(CG_MFMA_BNEG1, Apr, Api, A2r, A2i)
  #pragma unroll
  for (int mf = 0; mf < 2; ++mf)
    #pragma unroll
    for (int nf = 0; nf < 2; ++nf) {
      int col = bn + wc * 32 + nf * 16 + (lane & 15);
      #pragma unroll
      for (int r = 0; r < 4; ++r) {
        int rowg = bm + wr * 32 + mf * 16 + (lane >> 4) * 4 + r;
        size_t o = (size_t)rowg * 1024 + col;
        float vr = accR[mf][nf][r], vi = accI[mf][nf][r];
        if (z) { vr += bf2f(Nr2[o]); vi += bf2f(Ni2[o]); }   // +N
        Cr16[o] = f2bf(vr);
        Ci16[o] = f2bf(vi);
      }
    }
}

// --- V = 2*(T1@A4) + 2*T1 - I   (BNEG1, f32 out) ---------------------------
__global__ __launch_bounds__(TPB) void cgemm_v_k(
    const u16* __restrict__ T1r, const u16* __restrict__ T1i,
    const u16* __restrict__ A4r, const u16* __restrict__ A4i,
    float* __restrict__ Vr, float* __restrict__ Vi)
{
  int flat = swz8(blockIdx.x, 256);
  int bm = (flat >> 4) * 64, bn = (flat & 15) * 64;
  CG_PRELUDE
  CG_PIPELINE(CG_MFMA_BNEG1, T1r, T1i, A4r, A4i)
  #pragma unroll
  for (int mf = 0; mf < 2; ++mf)
    #pragma unroll
    for (int nf = 0; nf < 2; ++nf) {
      int col = bn + wc * 32 + nf * 16 + (lane & 15);
      #pragma unroll
      for (int r = 0; r < 4; ++r) {
        int rowg = bm + wr * 32 + mf * 16 + (lane >> 4) * 4 + r;
        size_t o = (size_t)rowg * 1024 + col;
        float dg = (rowg == col) ? 1.0f : 0.0f;
        Vr[o] = 2.0f * accR[mf][nf][r] + 2.0f * bf2f(T1r[o]) - dg;
        Vi[o] = 2.0f * accI[mf][nf][r] + 2.0f * bf2f(T1i[o]);
      }
    }
}

// ---------------------------------------------------------------------------
// Mt[d][k] = bf16( V[k][d]*exp(ls[d])*(1-alpha) + F[k][d]*alpha/32 )
// ---------------------------------------------------------------------------
__global__ __launch_bounds__(TPB) void build_mt_k(
    const float* __restrict__ Vr, const float* __restrict__ Vi,
    const float* __restrict__ log_sigma, const float* __restrict__ dft_weight,
    u16* __restrict__ Mtr, u16* __restrict__ Mti)
{
  __shared__ float Tr[64][65], Ti[64][65];
  int tid = threadIdx.x;
  int k0 = blockIdx.x * 64, d0 = blockIdx.y * 64;
  int c = tid & 63, r4 = tid >> 6;
  for (int p = 0; p < 16; ++p) {
    int r = r4 + p * 4;                       // local k index
    Tr[r][c] = Vr[(size_t)(k0 + r) * 1024 + d0 + c];
    Ti[r][c] = Vi[(size_t)(k0 + r) * 1024 + d0 + c];
  }
  __syncthreads();
  float alpha = sigmoidf_(dft_weight[0]);
  const float isq = 0.03125f * alpha;
  for (int p = 0; p < 16; ++p) {
    int dl = r4 + p * 4;                      // local d index (output row)
    int d = d0 + dl, k = k0 + c;
    float w1 = expf(log_sigma[d]) * (1.0f - alpha);
    int mm = (k * d) & 1023;
    float ang = -6.283185307179586f * (float)mm * (1.0f / 1024.0f);
    float sn, cs;
    sincosf(ang, &sn, &cs);
    size_t o = (size_t)d * 1024 + k;
    Mtr[o] = f2bf(Tr[c][dl] * w1 + cs * isq);
    Mti[o] = f2bf(Ti[c][dl] * w1 + sn * isq);
  }
}

// ---------------------------------------------------------------------------
// X f32 -> bf16 plane (vectorized, once)
// ---------------------------------------------------------------------------
__global__ __launch_bounds__(TPB) void xconv_k(
    const float* __restrict__ X, u16* __restrict__ Xb)
{
  int idx = (blockIdx.x * TPB + threadIdx.x) << 3;    // 8 per thread
  float4 a = *(const float4*)(X + idx);
  float4 b = *(const float4*)(X + idx + 4);
  u16 tmp[8];
  pack8(a, b, tmp);
  *(bf8v*)(Xb + idx) = *(bf8v*)tmp;
}

// ---------------------------------------------------------------------------
// per-d constants: op_decay, op_forcing, base_var
// ---------------------------------------------------------------------------
__global__ __launch_bounds__(TPB) void prep_k(
    const float* __restrict__ ld, const float* __restrict__ lf,
    const float* __restrict__ law_re, const float* __restrict__ law_im,
    const float* __restrict__ dt, const float* __restrict__ base_noise,
    float* __restrict__ od_re, float* __restrict__ od_im,
    float* __restrict__ of_re, float* __restrict__ of_im,
    float* __restrict__ bvar)
{
  int d = blockIdx.x * TPB + threadIdx.x;
  float dtr = dt[0];                              // DT_REF = 1.0
  float lre = tanhf(-expf(ld[d]) + law_re[d]) * 0.3f;
  float lim = lf[d] + law_im[d];
  float er = expf(lre * dtr);
  float sn, cs;
  sincosf(lim * dtr, &sn, &cs);
  float odr = er * cs, odi = er * sn;
  od_re[d] = odr;  od_im[d] = odi;
  float numr = odr - 1.0f, numi = odi;
  float denr = lre + 1e-8f, deni = lim;
  float inv = 1.0f / (denr * denr + deni * deni);
  of_re[d] = (numr * denr + numi * deni) * inv;
  of_im[d] = (numi * denr - numr * deni) * inv;
  float bn = base_noise[0];
  float bv = bn * bn * expm1f(2.0f * lre * dtr) / (2.0f * lre + 1e-8f);
  bvar[d] = fmaxf(bv, 0.0f);
}

// ---------------------------------------------------------------------------
// Wu1, Wu2 f32 -> bf16 planes
// ---------------------------------------------------------------------------
__global__ __launch_bounds__(TPB) void conv_w_k(
    const float* __restrict__ Wu1, const float* __restrict__ Wu2,
    u16* __restrict__ Wu1b, u16* __restrict__ Wu2b)
{
  int idx = blockIdx.x * TPB + threadIdx.x;     // 2 * 262144
  if (idx < 262144) Wu1b[idx] = f2bf(Wu1[idx]);
  else              Wu2b[idx - 262144] = f2bf(Wu2[idx - 262144]);
}

// ---------------------------------------------------------------------------
// M=16 split-K MFMA GEMM (partials) ; reduce adds bias (+sigmoid)
// ---------------------------------------------------------------------------
__global__ __launch_bounds__(TPB) void sgemm16_k(
    const float* __restrict__ A0, const float* __restrict__ A1,
    const float* __restrict__ Bw, float* __restrict__ Pp, int N)
{
  __shared__ __align__(16) u16 lds[2 * BUF1];
  int tid = threadIdx.x;
  int c0 = blockIdx.x * 64;
  int kbase = blockIdx.y * 256;
  int lane = tid & 63;
  int w = tid >> 6;
  int row = tid >> 2, kq = (tid & 3) << 3;

  f32x4 acc = {};
  float4 pb0, pb1;

  auto gload = [&](int k0) {
    const float* p = Bw + (size_t)(c0 + row) * 2048 + k0 + kq;
    pb0 = *(const float4*)p; pb1 = *(const float4*)(p + 4);
  };
  auto stolds = [&](int buf) {
    pack8(pb0, pb1, lds + buf * BUF1 + row * LSTR + kq);
  };
  auto compute = [&](int buf, int k0) {
    int ar = lane & 15;
    int ko = (lane >> 4) * 8;
    const float* ap = (k0 < 1024) ? (A0 + (size_t)ar * 1024 + k0 + ko)
                                  : (A1 + (size_t)ar * 1024 + k0 + ko - 1024);
    float4 a0 = *(const float4*)ap, a1 = *(const float4*)(ap + 4);
    u16 abuf[8];
    pack8(a0, a1, abuf);
    bf8v af = *(bf8v*)abuf;
    const u16* L = lds + buf * BUF1;
    bf8v bfr = *(const bf8v*)(L + (w * 16 + (lane & 15)) * LSTR + ko);
    acc = __builtin_amdgcn_mfma_f32_16x16x32_bf16(af, bfr, acc, 0, 0, 0);
  };

  gload(kbase); stolds(0); __syncthreads();
  int cur = 0;
  for (int t = 0; t < 8; ++t) {
    int k0 = kbase + t * 32;
    if (t < 7) gload(k0 + 32);
    compute(cur, k0);
    if (t < 7) stolds(cur ^ 1);
    __syncthreads();
    cur ^= 1;
  }

  int c = c0 + w * 16 + (lane & 15);
  #pragma unroll
  for (int r = 0; r < 4; ++r) {
    int rr = (lane >> 4) * 4 + r;
    Pp[((size_t)blockIdx.y * 16 + rr) * N + c] = acc[r];
  }
}

__global__ __launch_bounds__(TPB) void red16_k(
    const float* __restrict__ Pp, const float* __restrict__ bias,
    float* __restrict__ out, int N, int act)
{
  int idx = blockIdx.x * TPB + threadIdx.x;   // 16*N
  int c = idx & (N - 1);
  float v = bias[c];
  #pragma unroll
  for (int s = 0; s < 8; ++s) v += Pp[(size_t)s * 16 * N + idx];
  if (act == 1) v = sigmoidf_(v);
  out[idx] = v;
}

// ---------------------------------------------------------------------------
// flux_next = flux*fdecay + update ; FN planes + f32 output 1 = Re(flux_next)
// ---------------------------------------------------------------------------
__global__ __launch_bounds__(TPB) void flux_k(
    const float* __restrict__ xin,
    const float* __restrict__ flux_re, const float* __restrict__ flux_im,
    const float* __restrict__ decay_re, const float* __restrict__ decay_im,
    float* __restrict__ FNr, float* __restrict__ FNi,
    float* __restrict__ out1)
{
  int idx = blockIdx.x * TPB + threadIdx.x;     // 16 * 1024
  int b = idx >> 10, d = idx & 1023;
  float fdr = sigmoidf_(decay_re[d]);
  float fdi = decay_im[d];
  float fr = flux_re[idx], fi = flux_im[idx];
  float ur = xin[b * 2048 + d], ui = xin[b * 2048 + 1024 + d];
  float nr = fr * fdr - fi * fdi + ur;
  float ni = fr * fdi + fi * fdr + ui;
  FNr[idx] = nr;  FNi[idx] = ni;
  out1[idx] = nr;                                // f32, real part only
}

// ---------------------------------------------------------------------------
// x_tilde = Xb @ M + h_next epilogue -> Hrb bf16.
// 128x64 tile, 4 waves each computing 64x32 (mf=4, nf=2). BK=64, 2-buffer.
// ---------------------------------------------------------------------------
__global__ __launch_bounds__(TPB) void xmh_nt_k(
    const u16* __restrict__ Xb,
    const u16* __restrict__ Mtr, const u16* __restrict__ Mti,
    const float* __restrict__ gate, const float* __restrict__ proj,
    const float* __restrict__ od_re, const float* __restrict__ od_im,
    const float* __restrict__ of_re, const float* __restrict__ of_im,
    const float* __restrict__ hp_re, const float* __restrict__ hp_im,
    u16* __restrict__ Hrb)
{
  __shared__ __align__(16) u16 lds[2 * 16384];        // 64KB: A[128][64]+2xB[64][64]
  int flat = swz8(blockIdx.x, 512);
  int bm = (flat >> 4) * 128, bn = (flat & 15) * 64;
  int tid = threadIdx.x;
  int lane = tid & 63;
  int w = tid >> 6;
  int wr = w >> 1, wc = w & 1;
  int ln8 = lane >> 3;
  int ks2_ = (((lane & 7) ^ ln8) << 3);

  f32x4 accR[4][2] = {};
  f32x4 accI[4][2] = {};

#define XM_STAGE(buf, k0)                                                    \
  { u16* Lb = lds + (buf) * 16384;                                           \
    _Pragma("unroll")                                                        \
    for (int g = 0; g < 4; ++g)                                              \
      gload16(Xb + (size_t)(bm + w * 32 + g * 8 + ln8) * 1024 + (k0) + ks2_, \
              Lb + (w * 32 + g * 8) * 64);                                   \
    _Pragma("unroll")                                                        \
    for (int g = 0; g < 2; ++g) {                                            \
      gload16(Mtr + (size_t)(bn + w * 16 + g * 8 + ln8) * 1024 + (k0) + ks2_,\
              Lb + 8192 + (w * 16 + g * 8) * 64);                            \
      gload16(Mti + (size_t)(bn + w * 16 + g * 8 + ln8) * 1024 + (k0) + ks2_,\
              Lb + 12288 + (w * 16 + g * 8) * 64);                           \
    } }
#define XM_COMPUTE(buf, s)                                                   \
  { const u16* L = lds + (buf) * 16384;                                      \
    int kq = lane >> 4;                                                      \
    bf8v a[4], br[2], bi[2];                                                 \
    _Pragma("unroll")                                                        \
    for (int mf = 0; mf < 4; ++mf)                                           \
      a[mf] = fragld2(L, wr * 64 + mf * 16 + (lane & 15), kq, s);            \
    _Pragma("unroll")                                                        \
    for (int nf = 0; nf < 2; ++nf) {                                         \
      br[nf] = fragld2(L + 8192,  wc * 32 + nf * 16 + (lane & 15), kq, s);   \
      bi[nf] = fragld2(L + 12288, wc * 32 + nf * 16 + (lane & 15), kq, s);   \
    }                                                                        \
    _Pragma("unroll")                                                        \
    for (int mf = 0; mf < 4; ++mf)                                           \
      _Pragma("unroll")                                                      \
      for (int nf = 0; nf < 2; ++nf) {                                       \
        accR[mf][nf] = __builtin_amdgcn_mfma_f32_16x16x32_bf16(a[mf], br[nf], accR[mf][nf], 0, 0, 0); \
        accI[mf][nf] = __builtin_amdgcn_mfma_f32_16x16x32_bf16(a[mf], bi[nf], accI[mf][nf], 0, 0, 0); \
      } }

  XM_STAGE(0, 0);
  #pragma unroll 1
  for (int t = 0; t < 16; ++t) {
    int bufc = t & 1;
    if (t + 1 < 16) { XM_STAGE(bufc ^ 1, (t + 1) * 64); WAITV(8); }
    else            { WAITV(0); }
    __builtin_amdgcn_sched_barrier(0);
    __builtin_amdgcn_s_barrier();
    __builtin_amdgcn_s_setprio(1);
    XM_COMPUTE(bufc, 0)
    XM_COMPUTE(bufc, 1)
    __builtin_amdgcn_s_setprio(0);
    __builtin_amdgcn_sched_barrier(0);
    __builtin_amdgcn_s_barrier();
  }

  #pragma unroll
  for (int mf = 0; mf < 4; ++mf)
    #pragma unroll
    for (int nf = 0; nf < 2; ++nf) {
      int c = bn + wc * 32 + nf * 16 + (lane & 15);
      #pragma unroll
      for (int r = 0; r < 4; ++r) {
        int t = bm + wr * 64 + mf * 16 + (lane >> 4) * 4 + r;
        int b = t >> 8;                         // 128-row tile never straddles batch
        float g  = gate[b * 1024 + c];
        float sr = proj[b * 2048 + c];
        float si = proj[b * 2048 + 1024 + c];
        float fr = accR[mf][nf][r] * g + sr * (1.0f - g);
        float fi = accI[mf][nf][r] * g + si * (1.0f - g);
        float odr = od_re[c], odi = od_im[c];
        float ofr = of_re[c], ofi = of_im[c];
        size_t off = (size_t)t * 1024 + c;
        float pr = hp_re[off], pi = hp_im[off];
        Hrb[off] = f2bf(pr * odr - pi * odi + fr * ofr - fi * ofi);
      }
    }
}

// ---------------------------------------------------------------------------
// real NT GEMM, bf16: C = A@B^T.  KI = K/32.  3-buffer counted-vmcnt, BK=32.
// EPI=0 (mlp1): silu->bf16 direct.  EPI=2 (u): softplus->bf16 via LDS tile.
// ---------------------------------------------------------------------------
template<int KI, int EPI>
__global__ __launch_bounds__(TPB) void rgemm_nt_k(
    const u16* __restrict__ A, const u16* __restrict__ B,
    const float* __restrict__ bias,
    u16* __restrict__ C16, int nbxl, int total)
{
  __shared__ __align__(16) u16 lds[3 * 2 * PSZ];   // 24KB (ct needs 17.4KB)
  const int K = KI * 32;
  int tid = threadIdx.x;
  int flat = swz8(blockIdx.x, total);
  int bm = (flat >> nbxl) * 64;
  int bn = (flat & ((1 << nbxl) - 1)) * 64;
  const int N = 64 << nbxl;
  int lane = tid & 63;
  int wr = (tid >> 7) & 1, wc = (tid >> 6) & 1;
  int lr_ = ((tid & 63) >> 2) + ((tid >> 6) << 4);
  int ks_ = (((tid & 3) ^ ((tid >> 3) & 3)) << 3);
  u16* Lw_ = lds + ((tid >> 6) << 9);

  f32x4 acc[2][2] = {};

#define RG_STAGE(buf, k0)                                                    \
  { u16* Lb = Lw_ + (buf) * (2 * PSZ);                                       \
    gload16(A + (size_t)(bm + lr_) * K + (k0) + ks_, Lb + 0 * PSZ);          \
    gload16(B + (size_t)(bn + lr_) * K + (k0) + ks_, Lb + 1 * PSZ); }
#define RG_COMPUTE(buf)                                                      \
  { const u16* L = lds + (buf) * (2 * PSZ);                                  \
    int rA = wr * 32 + (lane & 15);                                          \
    int rB = wc * 32 + (lane & 15);                                          \
    int kq = lane >> 4;                                                      \
    bf8v a[2], b[2];                                                         \
    a[0] = fragld(L + 0 * PSZ, rA, kq);  a[1] = fragld(L + 0 * PSZ, rA + 16, kq); \
    b[0] = fragld(L + 1 * PSZ, rB, kq);  b[1] = fragld(L + 1 * PSZ, rB + 16, kq); \
    _Pragma("unroll")                                                        \
    for (int mf = 0; mf < 2; ++mf)                                           \
      _Pragma("unroll")                                                      \
      for (int nf = 0; nf < 2; ++nf)                                         \
        acc[mf][nf] = __builtin_amdgcn_mfma_f32_16x16x32_bf16(a[mf], b[nf], acc[mf][nf], 0, 0, 0); }

  RG_STAGE(0, 0);
  RG_STAGE(1, 32);
  #pragma unroll 1
  for (int t = 0; t < KI; ++t) {
    int bufc = t % 3;
    if (t + 2 < KI) { RG_STAGE((t + 2) % 3, (t + 2) * 32); }
    if (t + 2 < KI)      { WAITV(4); }
    else if (t + 1 < KI) { WAITV(2); }
    else                 { WAITV(0); }
    __builtin_amdgcn_sched_barrier(0);
    __builtin_amdgcn_s_barrier();
    __builtin_amdgcn_s_setprio(1);
    RG_COMPUTE(bufc)
    __builtin_amdgcn_s_setprio(0);
    __builtin_amdgcn_sched_barrier(0);
    __builtin_amdgcn_s_barrier();
  }

  if constexpr (EPI == 0) {
    #pragma unroll
    for (int mf = 0; mf < 2; ++mf)
      #pragma unroll
      for (int nf = 0; nf < 2; ++nf) {
        int c = bn + wc * 32 + nf * 16 + (lane & 15);
        #pragma unroll
        for (int r = 0; r < 4; ++r) {
          int t = bm + wr * 32 + mf * 16 + (lane >> 4) * 4 + r;
          float v = acc[mf][nf][r] + bias[c];
          v = v * sigmoidf_(v);                       // silu (fast exp)
          C16[(size_t)t * N + c] = f2bf(v);
        }
      }
  } else {
    // acc -> LDS f32 tile, then row-contiguous packed-bf16 softplus stores
    float* ct = (float*)lds;
    __syncthreads();
    #pragma unroll
    for (int mf = 0; mf < 2; ++mf)
      #pragma unroll
      for (int nf = 0; nf < 2; ++nf) {
        int rbase = wr * 32 + mf * 16 + (lane >> 4) * 4;
        int cc = wc * 32 + nf * 16 + (lane & 15);
        #pragma unroll
        for (int r = 0; r < 4; ++r)
          ct[(rbase + r) * CSTR + cc] = acc[mf][nf][r];
      }
    __syncthreads();
    int w = tid >> 6, l = tid & 63;
    int lcol = (l & 15) * 4;
    #pragma unroll
    for (int p = 0; p < 4; ++p) {
      int lrow = w * 16 + p * 4 + (l >> 4);
      int t = bm + lrow;
      int c = bn + lcol;
      float4 v4 = *(float4*)&ct[lrow * CSTR + lcol];
      float4 bi4 = *(const float4*)(bias + c);
      float u0 = spf_(v4.x + bi4.x);
      float u1 = spf_(v4.y + bi4.y);
      float u2 = spf_(v4.z + bi4.z);
      float u3 = spf_(v4.w + bi4.w);
      *(uint2*)(C16 + (size_t)t * N + c) = packbf4(u0, u1, u2, u3);
    }
  }
}

// ---------------------------------------------------------------------------
// out0 = Hrb + nre * sqrt(bvar * u) * sqrt(0.5)   (pure elementwise, x8)
// ---------------------------------------------------------------------------
__global__ __launch_bounds__(TPB) void fin_k(
    const u16* __restrict__ Hrb, const u16* __restrict__ ub,
    const float* __restrict__ nre, const float* __restrict__ bvar,
    float* __restrict__ out0)
{
  int idx = (blockIdx.x * TPB + threadIdx.x) << 3;    // 8 per thread
  int c = idx & 1023;
  bf8v hb = *(const bf8v*)(Hrb + idx);
  bf8v uv = *(const bf8v*)(ub + idx);
  float4 n0 = *(const float4*)(nre + idx);
  float4 n1 = *(const float4*)(nre + idx + 4);
  float4 b0 = *(const float4*)(bvar + c);
  float4 b1 = *(const float4*)(bvar + c + 4);
  float4 o0, o1;
  const float s2 = 0.7071067811865476f;
  #pragma unroll
  for (int j = 0; j < 4; ++j) {
    float sc = sqrtf(((const float*)&b0)[j] * bf2f((u16)uv[j])) * s2;
    ((float*)&o0)[j] = bf2f((u16)hb[j]) + ((const float*)&n0)[j] * sc;
  }
  #pragma unroll
  for (int j = 0; j < 4; ++j) {
    float sc = sqrtf(((const float*)&b1)[j] * bf2f((u16)uv[4 + j])) * s2;
    ((float*)&o1)[j] = bf2f((u16)hb[4 + j]) + ((const float*)&n1)[j] * sc;
  }
  *(float4*)(out0 + idx)     = o0;
  *(float4*)(out0 + idx + 4) = o1;
}

// ---------------------------------------------------------------------------
extern "C" void kernel_launch(void* const* d_in, const int* in_sizes, int n_in,
                              void* d_out, int out_size, void* d_ws, size_t ws_size,
                              hipStream_t stream) {
  (void)in_sizes; (void)n_in; (void)out_size;

  const float* x_input    = (const float*)d_in[0];
  const float* h_prev_re  = (const float*)d_in[1];
  const float* h_prev_im  = (const float*)d_in[2];
  const float* xg_re      = (const float*)d_in[3];
  const float* xg_im      = (const float*)d_in[4];
  const float* flux_re    = (const float*)d_in[5];
  const float* flux_im    = (const float*)d_in[6];
  const float* dt         = (const float*)d_in[7];
  const float* v_raw_re   = (const float*)d_in[10];
  const float* v_raw_im   = (const float*)d_in[11];
  const float* log_sigma  = (const float*)d_in[12];
  const float* dft_weight = (const float*)d_in[13];
  const float* decay_re   = (const float*)d_in[14];
  const float* decay_im   = (const float*)d_in[15];
  const float* Wi_in      = (const float*)d_in[16];
  const float* bi         = (const float*)d_in[17];
  const float* Wo         = (const float*)d_in[18];
  const float* bo         = (const float*)d_in[19];
  const float* Wg         = (const float*)d_in[20];
  const float* bg         = (const float*)d_in[21];
  const float* ld         = (const float*)d_in[22];
  const float* lf         = (const float*)d_in[23];
  const float* law_re     = (const float*)d_in[24];
  const float* law_im     = (const float*)d_in[25];
  const float* base_noise = (const float*)d_in[26];
  const float* Wu1        = (const float*)d_in[27];
  const float* bu1        = (const float*)d_in[28];
  const float* Wu2        = (const float*)d_in[29];
  const float* bu2        = (const float*)d_in[30];
  const float* noise_re   = (const float*)d_in[31];

  // --- workspace: 16 bf16-sized planes (2MB each) = 32MB --------------------
  const size_t PL16 = 1024ull * 1024ull;        // u16 per plane
  if (ws_size < 16 * PL16 * 2) return;          // too small -> zeros (diagnostic)

  u16* P = (u16*)d_ws;
  u16* Ar  = P + 0 * PL16;   u16* Ai  = P + 1 * PL16;   // A       (dead after A2)
  u16* Nr  = P + 2 * PL16;   u16* Ni  = P + 3 * PL16;   // N = I-A (dead after pair)
  u16* A2r = P + 4 * PL16;   u16* A2i = P + 5 * PL16;   // dead after pair
  u16* A4r = P + 6 * PL16;   u16* A4i = P + 7 * PL16;   // dead after V
  u16* T1r = P + 8 * PL16;   u16* T1i = P + 9 * PL16;   // dead after V
  // liveness reuse (stream-ordered):
  float* Vr = (float*)(P + 0 * PL16);   // 8MB over P0..P3 (A,N dead)
  float* Vi = (float*)(P + 2 * PL16);
  u16* Mtr  = P + 8 * PL16;             // over T1 (dead after V)
  u16* Mti  = P + 9 * PL16;
  u16* Xb   = P + 4 * PL16;             // 8MB over A2,A4 (dead after V)
  float* Pp = (float*)(P + 0 * PL16);   // 1MB split-K partials (V dead after build_mt)
  u16* ub   = P + 0 * PL16;             // 8MB u-plane (Pp dead after red16 chain)
  u16* Hrb  = P + 10 * PL16;            // 8MB, P10..P13
  u16* mlp1b = P + 14 * PL16;           // 4096x256
  u16* Wu1b  = P + 15 * PL16;           // 262144 u16
  u16* Wu2b  = Wu1b + 262144;
  float* sm  = (float*)(P + 15 * PL16 + 524288);
  float* xin  = sm;                     // 16x2048
  float* proj = xin + 32768;            // 16x2048
  float* FNr  = proj + 32768;           // 16x1024
  float* FNi  = FNr + 16384;
  float* gate = FNi + 16384;            // 16x1024
  float* od_re = gate + 16384;
  float* od_im = od_re + 1024;
  float* of_re = od_im + 1024;
  float* of_im = of_re + 1024;
  float* bvar  = of_im + 1024;

  float* out0f = (float*)d_out;                       // 4096x1024 f32 (real)
  float* out1f = out0f + (size_t)4096 * 1024;         // 16x1024 f32 (real)

  // --- Cayley: V = 2*(I-A)(I+A^2)(I+A^4) - I, err <= 2.2e-3 -----------------
  build_a_k<<<4096, TPB, 0, stream>>>(v_raw_re, v_raw_im, Ar, Ai, Nr, Ni);
  cgemm_a2_k<<<256, TPB, 0, stream>>>(Ar, Ai, A2r, A2i);                 // A2 = A@A
  cgemm_pair_k<<<512, TPB, 0, stream>>>(A2r, A2i, Nr, Ni,                // A4 = A2@A2
                                        A4r, A4i, T1r, T1i);             // T1 = N@A2+N
  cgemm_v_k<<<256, TPB, 0, stream>>>(T1r, T1i, A4r, A4i, Vr, Vi);        // V
  build_mt_k<<<dim3(16, 16), TPB, 0, stream>>>(Vr, Vi, log_sigma, dft_weight, Mtr, Mti);
  xconv_k<<<2048, TPB, 0, stream>>>(x_input, Xb);

  // --- per-d constants + weight conversion ----------------------------------
  prep_k<<<4, TPB, 0, stream>>>(ld, lf, law_re, law_im, dt, base_noise,
                                od_re, od_im, of_re, of_im, bvar);
  conv_w_k<<<2048, TPB, 0, stream>>>(Wu1, Wu2, Wu1b, Wu2b);

  // --- B=16 chain: split-K MFMA gemms ---------------------------------------
  sgemm16_k<<<dim3(32, 8), TPB, 0, stream>>>(xg_re, xg_im, Wi_in, Pp, 2048);
  red16_k<<<128, TPB, 0, stream>>>(Pp, bi, xin, 2048, 0);
  flux_k<<<64, TPB, 0, stream>>>(xin, flux_re, flux_im, decay_re, decay_im,
                                 FNr, FNi, out1f);
  sgemm16_k<<<dim3(32, 8), TPB, 0, stream>>>(FNr, FNi, Wo, Pp, 2048);
  red16_k<<<128, TPB, 0, stream>>>(Pp, bo, proj, 2048, 0);
  sgemm16_k<<<dim3(16, 8), TPB, 0, stream>>>(FNr, FNi, Wg, Pp, 1024);
  red16_k<<<64, TPB, 0, stream>>>(Pp, bg, gate, 1024, 1);

  // --- x_tilde = Xb@M fused with h_next epilogue -> Hrb bf16 (128x64 tile) --
  xmh_nt_k<<<512, TPB, 0, stream>>>(Xb, Mtr, Mti, gate, proj,
                                    od_re, od_im, of_re, of_im,
                                    h_prev_re, h_prev_im, Hrb);

  // --- u-MLP (MFMA) + elementwise final -------------------------------------
  rgemm_nt_k<32, 0><<<256, TPB, 0, stream>>>(Hrb, Wu1b, bu1, mlp1b, 2, 256);
  rgemm_nt_k<8, 2><<<1024, TPB, 0, stream>>>(mlp1b, Wu2b, bu2, ub, 4, 1024);
  fin_k<<<2048, TPB, 0, stream>>>(Hrb, ub, noise_re, bvar, out0f);
}

// Round 19
// 152.648 us; speedup vs baseline: 1.2028x; 1.1271x over previous
//
#include <hip/hip_runtime.h>
#include <cstddef>

#define TPB 256

typedef short bf8v  __attribute__((ext_vector_type(8)));   // 8 bf16 bit-patterns
typedef float f32x4 __attribute__((ext_vector_type(4)));
typedef unsigned short u16;

#define PSZ 2048     // u16 per LDS plane [64][32] (rgemm staging)
#define PSZ2 4096    // u16 per LDS plane [64][64] (BK=64 staging)
#define LSTR 40      // legacy stride for sgemm16 staging
#define BUF1 2560
#define CSTR 68      // f32 LDS epilogue-tile row stride

static __device__ __forceinline__ u16 f2bf(float x) {
  unsigned int u = __float_as_uint(x);
  u = (u + 0x7FFFu + ((u >> 16) & 1u)) >> 16;   // RNE f32 -> bf16
  return (u16)u;
}
static __device__ __forceinline__ float bf2f(u16 x) {
  return __uint_as_float(((unsigned int)x) << 16);
}
static __device__ __forceinline__ float sigmoidf_(float x) {
  return 1.0f / (1.0f + __expf(-x));            // fast exp (v_exp_f32)
}
static __device__ __forceinline__ float spf_(float v) {   // fast softplus
  return (v > 15.0f) ? v : __logf(1.0f + __expf(v));
}
static __device__ __forceinline__ bf8v neg8(bf8v a) {
  #pragma unroll
  for (int i = 0; i < 8; ++i) a[i] ^= (short)0x8000;
  return a;
}
static __device__ __forceinline__ void pack8(const float4& x, const float4& y,
                                             u16* dst) {
  unsigned int* d = (unsigned int*)dst;
  d[0] = ((unsigned)f2bf(x.y) << 16) | f2bf(x.x);
  d[1] = ((unsigned)f2bf(x.w) << 16) | f2bf(x.z);
  d[2] = ((unsigned)f2bf(y.y) << 16) | f2bf(y.x);
  d[3] = ((unsigned)f2bf(y.w) << 16) | f2bf(y.z);
}
static __device__ __forceinline__ uint2 packbf4(float a, float b, float c, float d) {
  uint2 r;
  r.x = ((unsigned)f2bf(b) << 16) | f2bf(a);
  r.y = ((unsigned)f2bf(d) << 16) | f2bf(c);
  return r;
}
// async global->LDS, 16B per lane; LDS dest is wave-uniform base + lane*16
static __device__ __forceinline__ void gload16(const u16* g, u16* l) {
  __builtin_amdgcn_global_load_lds((const __attribute__((address_space(1))) void*)g,
                                   (__attribute__((address_space(3))) void*)l,
                                   16, 0, 0);
}
// BK=32 fragment read with k-chunk XOR swizzle (rgemm path)
static __device__ __forceinline__ bf8v fragld(const u16* plane, int r, int kq) {
  int kb = (kq << 4) ^ (((r >> 1) & 3) << 4);
  return *(const bf8v*)(plane + r * 32 + (kb >> 1));
}
// BK=64 fragment read: global chunk (s*4+kq) at row r lives at chunk^(r&7)
static __device__ __forceinline__ bf8v fragld2(const u16* plane, int r, int kq, int s) {
  int ch = ((s << 2) + kq) ^ (r & 7);
  return *(const bf8v*)(plane + r * 64 + (ch << 3));
}
// XCD-aware bijective block swizzle (T % 8 == 0)
static __device__ __forceinline__ int swz8(int flat, int T) {
  return (flat & 7) * (T >> 3) + (flat >> 3);
}

#define WAITV(n) asm volatile("s_waitcnt vmcnt(" #n ")" ::: "memory")

// ---------------------------------------------------------------------------
// A = (v - v^T)re + i(v + v^T)im ; N = I - A   -> bf16 planes
// ---------------------------------------------------------------------------
__global__ __launch_bounds__(TPB) void build_a_k(
    const float* __restrict__ vre, const float* __restrict__ vim,
    u16* __restrict__ Ar, u16* __restrict__ Ai,
    u16* __restrict__ Nr, u16* __restrict__ Ni)
{
  int idx = blockIdx.x * TPB + threadIdx.x;
  int i = idx >> 10, j = idx & 1023;
  float ar = vre[idx] - vre[j * 1024 + i];
  float ai = vim[idx] + vim[j * 1024 + i];
  float dg = (i == j) ? 1.0f : 0.0f;
  Ar[idx] = f2bf(ar);       Ai[idx] = f2bf(ai);
  Nr[idx] = f2bf(dg - ar);  Ni[idx] = f2bf(-ai);
}

// ---------------------------------------------------------------------------
// complex-NT, BK=64, 2-buffer counted-vmcnt pipeline (16 phases, 32 MFMA each)
//   BNEG=0 (B-plane = A):     B_true = (-b^r, +b^i)
//   BNEG=1 (B-plane = A^2k):  B_true = (+b^r, -b^i)
// ---------------------------------------------------------------------------
#define CG_PRELUDE                                                           \
  __shared__ __align__(16) u16 lds[2 * 4 * PSZ2];       /* 64KB */           \
  int tid = threadIdx.x;                                                     \
  int lane = tid & 63;                                                       \
  int wr = (tid >> 7) & 1, wc = (tid >> 6) & 1;                              \
  int lr8_ = ((tid & 63) >> 3) + ((tid >> 6) << 4);     /* w*16 + lane>>3 */ \
  int ks2_ = (((lane & 7) ^ (lane >> 3)) << 3);                              \
  u16* Lw_ = lds + ((tid >> 6) << 10);                  /* w*16 rows * 64 */ \
  f32x4 accR[2][2] = {};                                                     \
  f32x4 accI[2][2] = {};

#define CG_STAGE(buf, k0, PAr, PAi, PBr, PBi)                                \
  { u16* Lb = Lw_ + (buf) * (4 * PSZ2);                                      \
    gload16((PAr) + (size_t)(bm + lr8_) * 1024 + (k0) + ks2_,     Lb + 0 * PSZ2);       \
    gload16((PAr) + (size_t)(bm + lr8_ + 8) * 1024 + (k0) + ks2_, Lb + 0 * PSZ2 + 512); \
    gload16((PAi) + (size_t)(bm + lr8_) * 1024 + (k0) + ks2_,     Lb + 1 * PSZ2);       \
    gload16((PAi) + (size_t)(bm + lr8_ + 8) * 1024 + (k0) + ks2_, Lb + 1 * PSZ2 + 512); \
    gload16((PBr) + (size_t)(bn + lr8_) * 1024 + (k0) + ks2_,     Lb + 2 * PSZ2);       \
    gload16((PBr) + (size_t)(bn + lr8_ + 8) * 1024 + (k0) + ks2_, Lb + 2 * PSZ2 + 512); \
    gload16((PBi) + (size_t)(bn + lr8_) * 1024 + (k0) + ks2_,     Lb + 3 * PSZ2);       \
    gload16((PBi) + (size_t)(bn + lr8_ + 8) * 1024 + (k0) + ks2_, Lb + 3 * PSZ2 + 512); }

#define CG_FRAGS(buf, s)                                                     \
  const u16* L = lds + (buf) * (4 * PSZ2);                                   \
  int rA = wr * 32 + (lane & 15);                                            \
  int rB = wc * 32 + (lane & 15);                                            \
  int kq = lane >> 4;                                                        \
  bf8v ar[2], ai[2], br[2], bi[2];                                           \
  ar[0] = fragld2(L + 0 * PSZ2, rA, kq, s);  ar[1] = fragld2(L + 0 * PSZ2, rA + 16, kq, s); \
  ai[0] = fragld2(L + 1 * PSZ2, rA, kq, s);  ai[1] = fragld2(L + 1 * PSZ2, rA + 16, kq, s); \
  br[0] = fragld2(L + 2 * PSZ2, rB, kq, s);  br[1] = fragld2(L + 2 * PSZ2, rB + 16, kq, s); \
  bi[0] = fragld2(L + 3 * PSZ2, rB, kq, s);  bi[1] = fragld2(L + 3 * PSZ2, rB + 16, kq, s);

#define CG_MFMA_BNEG0                                                        \
  { bf8v nbr[2] = { neg8(br[0]), neg8(br[1]) };                              \
    bf8v nbi[2] = { neg8(bi[0]), neg8(bi[1]) };                              \
    _Pragma("unroll")                                                        \
    for (int mf = 0; mf < 2; ++mf)                                           \
      _Pragma("unroll")                                                      \
      for (int nf = 0; nf < 2; ++nf) {                                       \
        accR[mf][nf] = __builtin_amdgcn_mfma_f32_16x16x32_bf16(ar[mf], nbr[nf], accR[mf][nf], 0, 0, 0); \
        accR[mf][nf] = __builtin_amdgcn_mfma_f32_16x16x32_bf16(ai[mf], nbi[nf], accR[mf][nf], 0, 0, 0); \
        accI[mf][nf] = __builtin_amdgcn_mfma_f32_16x16x32_bf16(ar[mf], bi[nf],  accI[mf][nf], 0, 0, 0); \
        accI[mf][nf] = __builtin_amdgcn_mfma_f32_16x16x32_bf16(ai[mf], nbr[nf], accI[mf][nf], 0, 0, 0); \
      } }

#define CG_MFMA_BNEG1                                                        \
  { bf8v nbi[2] = { neg8(bi[0]), neg8(bi[1]) };                              \
    _Pragma("unroll")                                                        \
    for (int mf = 0; mf < 2; ++mf)                                           \
      _Pragma("unroll")                                                      \
      for (int nf = 0; nf < 2; ++nf) {                                       \
        accR[mf][nf] = __builtin_amdgcn_mfma_f32_16x16x32_bf16(ar[mf], br[nf],  accR[mf][nf], 0, 0, 0); \
        accR[mf][nf] = __builtin_amdgcn_mfma_f32_16x16x32_bf16(ai[mf], bi[nf],  accR[mf][nf], 0, 0, 0); \
        accI[mf][nf] = __builtin_amdgcn_mfma_f32_16x16x32_bf16(ar[mf], nbi[nf], accI[mf][nf], 0, 0, 0); \
        accI[mf][nf] = __builtin_amdgcn_mfma_f32_16x16x32_bf16(ai[mf], br[nf],  accI[mf][nf], 0, 0, 0); \
      } }

#define CG_PIPELINE(MFMA_OP, PAr, PAi, PBr, PBi)                             \
  CG_STAGE(0, 0, PAr, PAi, PBr, PBi);                                        \
  _Pragma("unroll 1")                                                        \
  for (int t = 0; t < 16; ++t) {                                             \
    int bufc = t & 1;                                                        \
    if (t + 1 < 16) { CG_STAGE(bufc ^ 1, (t + 1) * 64, PAr, PAi, PBr, PBi);  \
                      WAITV(8); }                                            \
    else            { WAITV(0); }                                            \
    __builtin_amdgcn_sched_barrier(0);                                       \
    __builtin_amdgcn_s_barrier();                                            \
    __builtin_amdgcn_s_setprio(1);                                           \
    { CG_FRAGS(bufc, 0) MFMA_OP }                                            \
    { CG_FRAGS(bufc, 1) MFMA_OP }                                            \
    __builtin_amdgcn_s_setprio(0);                                           \
    __builtin_amdgcn_sched_barrier(0);                                       \
    __builtin_amdgcn_s_barrier();                                            \
  }

// --- A2 = A@A  (BNEG0, bf16 out) -------------------------------------------
__global__ __launch_bounds__(TPB) void cgemm_a2_k(
    const u16* __restrict__ Apr, const u16* __restrict__ Api,
    u16* __restrict__ Cr16, u16* __restrict__ Ci16)
{
  int flat = swz8(blockIdx.x, 256);
  int bm = (flat >> 4) * 64, bn = (flat & 15) * 64;
  CG_PRELUDE
  CG_PIPELINE(CG_MFMA_BNEG0, Apr, Api, Apr, Api)
  #pragma unroll
  for (int mf = 0; mf < 2; ++mf)
    #pragma unroll
    for (int nf = 0; nf < 2; ++nf) {
      int col = bn + wc * 32 + nf * 16 + (lane & 15);
      #pragma unroll
      for (int r = 0; r < 4; ++r) {
        int rowg = bm + wr * 32 + mf * 16 + (lane >> 4) * 4 + r;
        size_t o = (size_t)rowg * 1024 + col;
        Cr16[o] = f2bf(accR[mf][nf][r]);
        Ci16[o] = f2bf(accI[mf][nf][r]);
      }
    }
}

// --- batched: z=0: A4 = A2@A2 ; z=1: T1 = N@A2 + N   (BNEG1, bf16 out) -----
__global__ __launch_bounds__(TPB) void cgemm_pair_k(
    const u16* __restrict__ A2r, const u16* __restrict__ A2i,
    const u16* __restrict__ Nr2, const u16* __restrict__ Ni2,
    u16* __restrict__ A4r, u16* __restrict__ A4i,
    u16* __restrict__ T1r, u16* __restrict__ T1i)
{
  int flat = swz8(blockIdx.x, 512);
  int z = flat >> 8;
  int t8 = flat & 255;
  int bm = (t8 >> 4) * 64, bn = (t8 & 15) * 64;
  const u16* Apr = z ? Nr2 : A2r;
  const u16* Api = z ? Ni2 : A2i;
  u16* Cr16 = z ? T1r : A4r;
  u16* Ci16 = z ? T1i : A4i;
  CG_PRELUDE
  CG_PIPELINE(CG_MFMA_BNEG1, Apr, Api, A2r, A2i)
  #pragma unroll
  for (int mf = 0; mf < 2; ++mf)
    #pragma unroll
    for (int nf = 0; nf < 2; ++nf) {
      int col = bn + wc * 32 + nf * 16 + (lane & 15);
      #pragma unroll
      for (int r = 0; r < 4; ++r) {
        int rowg = bm + wr * 32 + mf * 16 + (lane >> 4) * 4 + r;
        size_t o = (size_t)rowg * 1024 + col;
        float vr = accR[mf][nf][r], vi = accI[mf][nf][r];
        if (z) { vr += bf2f(Nr2[o]); vi += bf2f(Ni2[o]); }   // +N
        Cr16[o] = f2bf(vr);
        Ci16[o] = f2bf(vi);
      }
    }
}

// --- V = 2*(T1@A4) + 2*T1 - I, fused Mt build (transposed bf16 out) --------
// Mt[d][k] = bf16( V[k][d]*exp(ls[d])*(1-alpha) + F[k][d]*alpha/32 )
__global__ __launch_bounds__(TPB) void cgemm_vmt_k(
    const u16* __restrict__ T1r, const u16* __restrict__ T1i,
    const u16* __restrict__ A4r, const u16* __restrict__ A4i,
    const float* __restrict__ log_sigma, const float* __restrict__ dft_weight,
    u16* __restrict__ Mtr, u16* __restrict__ Mti)
{
  int flat = swz8(blockIdx.x, 256);
  int bm = (flat >> 4) * 64, bn = (flat & 15) * 64;   // bm = k-range, bn = d-range
  CG_PRELUDE
  CG_PIPELINE(CG_MFMA_BNEG1, T1r, T1i, A4r, A4i)

  // fused Mt epilogue: compute in (k,d) position, transpose via LDS u16 tiles
  u16* mtLr = lds;              // [64][72] u16
  u16* mtLi = lds + 4608;
  __syncthreads();
  {
    float alpha = sigmoidf_(dft_weight[0]);
    const float isq = 0.03125f * alpha;
    #pragma unroll
    for (int mf = 0; mf < 2; ++mf)
      #pragma unroll
      for (int nf = 0; nf < 2; ++nf) {
        int dl = wc * 32 + nf * 16 + (lane & 15);     // local d
        int dgl = bn + dl;                            // global d
        float w1 = expf(log_sigma[dgl]) * (1.0f - alpha);
        #pragma unroll
        for (int r = 0; r < 4; ++r) {
          int kl = wr * 32 + mf * 16 + (lane >> 4) * 4 + r;   // local k
          int kgl = bm + kl;                                  // global k
          size_t o = (size_t)kgl * 1024 + dgl;
          float dg = (kgl == dgl) ? 1.0f : 0.0f;
          float vr = 2.0f * accR[mf][nf][r] + 2.0f * bf2f(T1r[o]) - dg;
          float vi = 2.0f * accI[mf][nf][r] + 2.0f * bf2f(T1i[o]);
          int mm = (kgl * dgl) & 1023;
          float ang = -6.283185307179586f * (float)mm * (1.0f / 1024.0f);
          float sn, cs;
          sincosf(ang, &sn, &cs);
          mtLr[dl * 72 + kl] = f2bf(vr * w1 + cs * isq);
          mtLi[dl * 72 + kl] = f2bf(vi * w1 + sn * isq);
        }
      }
  }
  __syncthreads();
  {
    int dl = tid >> 2, kl0 = (tid & 3) * 16;
    size_t o = (size_t)(bn + dl) * 1024 + bm + kl0;
    uint4* srcR = (uint4*)(mtLr + dl * 72 + kl0);
    uint4* srcI = (uint4*)(mtLi + dl * 72 + kl0);
    *(uint4*)(Mtr + o)     = srcR[0];
    *(uint4*)(Mtr + o + 8) = srcR[1];
    *(uint4*)(Mti + o)     = srcI[0];
    *(uint4*)(Mti + o + 8) = srcI[1];
  }
}

// ---------------------------------------------------------------------------
// fused converts + per-d constants:
// blocks [0,2048): x f32->bf16 ; [2048,2304): Wu1/Wu2 ; [2304,2308): prep
// ---------------------------------------------------------------------------
__global__ __launch_bounds__(TPB) void conv_all_k(
    const float* __restrict__ X, const float* __restrict__ Wu1,
    const float* __restrict__ Wu2,
    const float* __restrict__ ld, const float* __restrict__ lf,
    const float* __restrict__ law_re, const float* __restrict__ law_im,
    const float* __restrict__ dt, const float* __restrict__ base_noise,
    u16* __restrict__ Xb, u16* __restrict__ Wu1b, u16* __restrict__ Wu2b,
    float* __restrict__ od_re, float* __restrict__ od_im,
    float* __restrict__ of_re, float* __restrict__ of_im,
    float* __restrict__ bvar)
{
  int bx = blockIdx.x;
  if (bx < 2304) {
    int e = (bx * TPB + threadIdx.x) << 3;
    const float* src;
    u16* dst;
    if (e < 4194304)       { src = X + e;               dst = Xb + e; }
    else if (e < 4456448)  { src = Wu1 + (e - 4194304); dst = Wu1b + (e - 4194304); }
    else                   { src = Wu2 + (e - 4456448); dst = Wu2b + (e - 4456448); }
    float4 a = *(const float4*)src;
    float4 b = *(const float4*)(src + 4);
    u16 tmp[8];
    pack8(a, b, tmp);
    *(bf8v*)dst = *(bf8v*)tmp;
  } else {
    int d = (bx - 2304) * TPB + threadIdx.x;
    float dtr = dt[0];                              // DT_REF = 1.0
    float lre = tanhf(-expf(ld[d]) + law_re[d]) * 0.3f;
    float lim = lf[d] + law_im[d];
    float er = expf(lre * dtr);
    float sn, cs;
    sincosf(lim * dtr, &sn, &cs);
    float odr = er * cs, odi = er * sn;
    od_re[d] = odr;  od_im[d] = odi;
    float numr = odr - 1.0f, numi = odi;
    float denr = lre + 1e-8f, deni = lim;
    float inv = 1.0f / (denr * denr + deni * deni);
    of_re[d] = (numr * denr + numi * deni) * inv;
    of_im[d] = (numi * denr - numr * deni) * inv;
    float bn = base_noise[0];
    float bv = bn * bn * expm1f(2.0f * lre * dtr) / (2.0f * lre + 1e-8f);
    bvar[d] = fmaxf(bv, 0.0f);
  }
}

// ---------------------------------------------------------------------------
// M=16 split-K MFMA GEMM (partials), single-B variant (Wi)
// ---------------------------------------------------------------------------
__global__ __launch_bounds__(TPB) void sgemm16_k(
    const float* __restrict__ A0, const float* __restrict__ A1,
    const float* __restrict__ Bw, float* __restrict__ Pp, int N)
{
  __shared__ __align__(16) u16 lds[2 * BUF1];
  int tid = threadIdx.x;
  int c0 = blockIdx.x * 64;
  int kbase = blockIdx.y * 256;
  int lane = tid & 63;
  int w = tid >> 6;
  int row = tid >> 2, kq = (tid & 3) << 3;

  f32x4 acc = {};
  float4 pb0, pb1;

  auto gload = [&](int k0) {
    const float* p = Bw + (size_t)(c0 + row) * 2048 + k0 + kq;
    pb0 = *(const float4*)p; pb1 = *(const float4*)(p + 4);
  };
  auto stolds = [&](int buf) {
    pack8(pb0, pb1, lds + buf * BUF1 + row * LSTR + kq);
  };
  auto compute = [&](int buf, int k0) {
    int ar = lane & 15;
    int ko = (lane >> 4) * 8;
    const float* ap = (k0 < 1024) ? (A0 + (size_t)ar * 1024 + k0 + ko)
                                  : (A1 + (size_t)ar * 1024 + k0 + ko - 1024);
    float4 a0 = *(const float4*)ap, a1 = *(const float4*)(ap + 4);
    u16 abuf[8];
    pack8(a0, a1, abuf);
    bf8v af = *(bf8v*)abuf;
    const u16* L = lds + buf * BUF1;
    bf8v bfr = *(const bf8v*)(L + (w * 16 + (lane & 15)) * LSTR + ko);
    acc = __builtin_amdgcn_mfma_f32_16x16x32_bf16(af, bfr, acc, 0, 0, 0);
  };

  gload(kbase); stolds(0); __syncthreads();
  int cur = 0;
  for (int t = 0; t < 8; ++t) {
    int k0 = kbase + t * 32;
    if (t < 7) gload(k0 + 32);
    compute(cur, k0);
    if (t < 7) stolds(cur ^ 1);
    __syncthreads();
    cur ^= 1;
  }

  int c = c0 + w * 16 + (lane & 15);
  #pragma unroll
  for (int r = 0; r < 4; ++r) {
    int rr = (lane >> 4) * 4 + r;
    Pp[((size_t)blockIdx.y * 16 + rr) * N + c] = acc[r];
  }
}

// --- fused Wo+Wg split-K gemm: bx<32 -> Wo (N=2048), else Wg (N=1024) ------
__global__ __launch_bounds__(TPB) void sgemm16_wog_k(
    const float* __restrict__ A0, const float* __restrict__ A1,
    const float* __restrict__ Wo, const float* __restrict__ Wg,
    float* __restrict__ PpO, float* __restrict__ PpG)
{
  __shared__ __align__(16) u16 lds[2 * BUF1];
  int tid = threadIdx.x;
  int bx = blockIdx.x;
  const float* Bw = (bx < 32) ? Wo : Wg;
  float* Pp = (bx < 32) ? PpO : PpG;
  int N = (bx < 32) ? 2048 : 1024;
  int c0 = ((bx < 32) ? bx : (bx - 32)) * 64;
  int kbase = blockIdx.y * 256;
  int lane = tid & 63;
  int w = tid >> 6;
  int row = tid >> 2, kq = (tid & 3) << 3;

  f32x4 acc = {};
  float4 pb0, pb1;

  auto gload = [&](int k0) {
    const float* p = Bw + (size_t)(c0 + row) * 2048 + k0 + kq;
    pb0 = *(const float4*)p; pb1 = *(const float4*)(p + 4);
  };
  auto stolds = [&](int buf) {
    pack8(pb0, pb1, lds + buf * BUF1 + row * LSTR + kq);
  };
  auto compute = [&](int buf, int k0) {
    int ar = lane & 15;
    int ko = (lane >> 4) * 8;
    const float* ap = (k0 < 1024) ? (A0 + (size_t)ar * 1024 + k0 + ko)
                                  : (A1 + (size_t)ar * 1024 + k0 + ko - 1024);
    float4 a0 = *(const float4*)ap, a1 = *(const float4*)(ap + 4);
    u16 abuf[8];
    pack8(a0, a1, abuf);
    bf8v af = *(bf8v*)abuf;
    const u16* L = lds + buf * BUF1;
    bf8v bfr = *(const bf8v*)(L + (w * 16 + (lane & 15)) * LSTR + ko);
    acc = __builtin_amdgcn_mfma_f32_16x16x32_bf16(af, bfr, acc, 0, 0, 0);
  };

  gload(kbase); stolds(0); __syncthreads();
  int cur = 0;
  for (int t = 0; t < 8; ++t) {
    int k0 = kbase + t * 32;
    if (t < 7) gload(k0 + 32);
    compute(cur, k0);
    if (t < 7) stolds(cur ^ 1);
    __syncthreads();
    cur ^= 1;
  }

  int c = c0 + w * 16 + (lane & 15);
  #pragma unroll
  for (int r = 0; r < 4; ++r) {
    int rr = (lane >> 4) * 4 + r;
    Pp[((size_t)blockIdx.y * 16 + rr) * N + c] = acc[r];
  }
}

__global__ __launch_bounds__(TPB) void red16_k(
    const float* __restrict__ Pp, const float* __restrict__ bias,
    float* __restrict__ out, int N, int act)
{
  int idx = blockIdx.x * TPB + threadIdx.x;   // 16*N
  int c = idx & (N - 1);
  float v = bias[c];
  #pragma unroll
  for (int s = 0; s < 8; ++s) v += Pp[(size_t)s * 16 * N + idx];
  if (act == 1) v = sigmoidf_(v);
  out[idx] = v;
}

// --- fused reduce: idx<32768 -> proj (N=2048, +bo), else gate (sigmoid,+bg) -
__global__ __launch_bounds__(TPB) void red16_wog_k(
    const float* __restrict__ PpO, const float* __restrict__ PpG,
    const float* __restrict__ bo, const float* __restrict__ bg,
    float* __restrict__ proj, float* __restrict__ gate)
{
  int idx = blockIdx.x * TPB + threadIdx.x;   // 49152
  if (idx < 32768) {
    int c = idx & 2047;
    float v = bo[c];
    #pragma unroll
    for (int s = 0; s < 8; ++s) v += PpO[(size_t)s * 32768 + idx];
    proj[idx] = v;
  } else {
    int j = idx - 32768;
    int c = j & 1023;
    float v = bg[c];
    #pragma unroll
    for (int s = 0; s < 8; ++s) v += PpG[(size_t)s * 16384 + j];
    gate[j] = sigmoidf_(v);
  }
}

// ---------------------------------------------------------------------------
// flux_next = flux*fdecay + update ; FN planes + f32 output 1 = Re(flux_next)
// ---------------------------------------------------------------------------
__global__ __launch_bounds__(TPB) void flux_k(
    const float* __restrict__ xin,
    const float* __restrict__ flux_re, const float* __restrict__ flux_im,
    const float* __restrict__ decay_re, const float* __restrict__ decay_im,
    float* __restrict__ FNr, float* __restrict__ FNi,
    float* __restrict__ out1)
{
  int idx = blockIdx.x * TPB + threadIdx.x;     // 16 * 1024
  int b = idx >> 10, d = idx & 1023;
  float fdr = sigmoidf_(decay_re[d]);
  float fdi = decay_im[d];
  float fr = flux_re[idx], fi = flux_im[idx];
  float ur = xin[b * 2048 + d], ui = xin[b * 2048 + 1024 + d];
  float nr = fr * fdr - fi * fdi + ur;
  float ni = fr * fdi + fi * fdr + ui;
  FNr[idx] = nr;  FNi[idx] = ni;
  out1[idx] = nr;                                // f32, real part only
}

// ---------------------------------------------------------------------------
// x_tilde = Xb @ M + h_next epilogue -> Hrb bf16.
// 128x64 tile, 4 waves each computing 64x32 (mf=4, nf=2). BK=64, 2-buffer.
// ---------------------------------------------------------------------------
__global__ __launch_bounds__(TPB) void xmh_nt_k(
    const u16* __restrict__ Xb,
    const u16* __restrict__ Mtr, const u16* __restrict__ Mti,
    const float* __restrict__ gate, const float* __restrict__ proj,
    const float* __restrict__ od_re, const float* __restrict__ od_im,
    const float* __restrict__ of_re, const float* __restrict__ of_im,
    const float* __restrict__ hp_re, const float* __restrict__ hp_im,
    u16* __restrict__ Hrb)
{
  __shared__ __align__(16) u16 lds[2 * 16384];        // 64KB: A[128][64]+2xB[64][64]
  int flat = swz8(blockIdx.x, 512);
  int bm = (flat >> 4) * 128, bn = (flat & 15) * 64;
  int tid = threadIdx.x;
  int lane = tid & 63;
  int w = tid >> 6;
  int wr = w >> 1, wc = w & 1;
  int ln8 = lane >> 3;
  int ks2_ = (((lane & 7) ^ ln8) << 3);

  f32x4 accR[4][2] = {};
  f32x4 accI[4][2] = {};

#define XM_STAGE(buf, k0)                                                    \
  { u16* Lb = lds + (buf) * 16384;                                           \
    _Pragma("unroll")                                                        \
    for (int g = 0; g < 4; ++g)                                              \
      gload16(Xb + (size_t)(bm + w * 32 + g * 8 + ln8) * 1024 + (k0) + ks2_, \
              Lb + (w * 32 + g * 8) * 64);                                   \
    _Pragma("unroll")                                                        \
    for (int g = 0; g < 2; ++g) {                                            \
      gload16(Mtr + (size_t)(bn + w * 16 + g * 8 + ln8) * 1024 + (k0) + ks2_,\
              Lb + 8192 + (w * 16 + g * 8) * 64);                            \
      gload16(Mti + (size_t)(bn + w * 16 + g * 8 + ln8) * 1024 + (k0) + ks2_,\
              Lb + 12288 + (w * 16 + g * 8) * 64);                           \
    } }
#define XM_COMPUTE(buf, s)                                                   \
  { const u16* L = lds + (buf) * 16384;                                      \
    int kq = lane >> 4;                                                      \
    bf8v a[4], br[2], bi[2];                                                 \
    _Pragma("unroll")                                                        \
    for (int mf = 0; mf < 4; ++mf)                                           \
      a[mf] = fragld2(L, wr * 64 + mf * 16 + (lane & 15), kq, s);            \
    _Pragma("unroll")                                                        \
    for (int nf = 0; nf < 2; ++nf) {                                         \
      br[nf] = fragld2(L + 8192,  wc * 32 + nf * 16 + (lane & 15), kq, s);   \
      bi[nf] = fragld2(L + 12288, wc * 32 + nf * 16 + (lane & 15), kq, s);   \
    }                                                                        \
    _Pragma("unroll")                                                        \
    for (int mf = 0; mf < 4; ++mf)                                           \
      _Pragma("unroll")                                                      \
      for (int nf = 0; nf < 2; ++nf) {                                       \
        accR[mf][nf] = __builtin_amdgcn_mfma_f32_16x16x32_bf16(a[mf], br[nf], accR[mf][nf], 0, 0, 0); \
        accI[mf][nf] = __builtin_amdgcn_mfma_f32_16x16x32_bf16(a[mf], bi[nf], accI[mf][nf], 0, 0, 0); \
      } }

  XM_STAGE(0, 0);
  #pragma unroll 1
  for (int t = 0; t < 16; ++t) {
    int bufc = t & 1;
    if (t + 1 < 16) { XM_STAGE(bufc ^ 1, (t + 1) * 64); WAITV(8); }
    else            { WAITV(0); }
    __builtin_amdgcn_sched_barrier(0);
    __builtin_amdgcn_s_barrier();
    __builtin_amdgcn_s_setprio(1);
    XM_COMPUTE(bufc, 0)
    XM_COMPUTE(bufc, 1)
    __builtin_amdgcn_s_setprio(0);
    __builtin_amdgcn_sched_barrier(0);
    __builtin_amdgcn_s_barrier();
  }

  #pragma unroll
  for (int mf = 0; mf < 4; ++mf)
    #pragma unroll
    for (int nf = 0; nf < 2; ++nf) {
      int c = bn + wc * 32 + nf * 16 + (lane & 15);
      #pragma unroll
      for (int r = 0; r < 4; ++r) {
        int t = bm + wr * 64 + mf * 16 + (lane >> 4) * 4 + r;
        int b = t >> 8;                         // 128-row tile never straddles batch
        float g  = gate[b * 1024 + c];
        float sr = proj[b * 2048 + c];
        float si = proj[b * 2048 + 1024 + c];
        float fr = accR[mf][nf][r] * g + sr * (1.0f - g);
        float fi = accI[mf][nf][r] * g + si * (1.0f - g);
        float odr = od_re[c], odi = od_im[c];
        float ofr = of_re[c], ofi = of_im[c];
        size_t off = (size_t)t * 1024 + c;
        float pr = hp_re[off], pi = hp_im[off];
        Hrb[off] = f2bf(pr * odr - pi * odi + fr * ofr - fi * ofi);
      }
    }
}

// ---------------------------------------------------------------------------
// real NT GEMM, bf16: C = A@B^T.  KI = K/32.  3-buffer counted-vmcnt, BK=32.
// EPI=0 (mlp1): silu->bf16 direct.  EPI=2 (u): softplus->bf16 via LDS tile.
// ---------------------------------------------------------------------------
template<int KI, int EPI>
__global__ __launch_bounds__(TPB) void rgemm_nt_k(
    const u16* __restrict__ A, const u16* __restrict__ B,
    const float* __restrict__ bias,
    u16* __restrict__ C16, int nbxl, int total)
{
  __shared__ __align__(16) u16 lds[3 * 2 * PSZ];   // 24KB (ct needs 17.4KB)
  const int K = KI * 32;
  int tid = threadIdx.x;
  int flat = swz8(blockIdx.x, total);
  int bm = (flat >> nbxl) * 64;
  int bn = (flat & ((1 << nbxl) - 1)) * 64;
  const int N = 64 << nbxl;
  int lane = tid & 63;
  int wr = (tid >> 7) & 1, wc = (tid >> 6) & 1;
  int lr_ = ((tid & 63) >> 2) + ((tid >> 6) << 4);
  int ks_ = (((tid & 3) ^ ((tid >> 3) & 3)) << 3);
  u16* Lw_ = lds + ((tid >> 6) << 9);

  f32x4 acc[2][2] = {};

#define RG_STAGE(buf, k0)                                                    \
  { u16* Lb = Lw_ + (buf) * (2 * PSZ);                                       \
    gload16(A + (size_t)(bm + lr_) * K + (k0) + ks_, Lb + 0 * PSZ);          \
    gload16(B + (size_t)(bn + lr_) * K + (k0) + ks_, Lb + 1 * PSZ); }
#define RG_COMPUTE(buf)                                                      \
  { const u16* L = lds + (buf) * (2 * PSZ);                                  \
    int rA = wr * 32 + (lane & 15);                                          \
    int rB = wc * 32 + (lane & 15);                                          \
    int kq = lane >> 4;                                                      \
    bf8v a[2], b[2];                                                         \
    a[0] = fragld(L + 0 * PSZ, rA, kq);  a[1] = fragld(L + 0 * PSZ, rA + 16, kq); \
    b[0] = fragld(L + 1 * PSZ, rB, kq);  b[1] = fragld(L + 1 * PSZ, rB + 16, kq); \
    _Pragma("unroll")                                                        \
    for (int mf = 0; mf < 2; ++mf)                                           \
      _Pragma("unroll")                                                      \
      for (int nf = 0; nf < 2; ++nf)                                         \
        acc[mf][nf] = __builtin_amdgcn_mfma_f32_16x16x32_bf16(a[mf], b[nf], acc[mf][nf], 0, 0, 0); }

  RG_STAGE(0, 0);
  RG_STAGE(1, 32);
  #pragma unroll 1
  for (int t = 0; t < KI; ++t) {
    int bufc = t % 3;
    if (t + 2 < KI) { RG_STAGE((t + 2) % 3, (t + 2) * 32); }
    if (t + 2 < KI)      { WAITV(4); }
    else if (t + 1 < KI) { WAITV(2); }
    else                 { WAITV(0); }
    __builtin_amdgcn_sched_barrier(0);
    __builtin_amdgcn_s_barrier();
    __builtin_amdgcn_s_setprio(1);
    RG_COMPUTE(bufc)
    __builtin_amdgcn_s_setprio(0);
    __builtin_amdgcn_sched_barrier(0);
    __builtin_amdgcn_s_barrier();
  }

  if constexpr (EPI == 0) {
    #pragma unroll
    for (int mf = 0; mf < 2; ++mf)
      #pragma unroll
      for (int nf = 0; nf < 2; ++nf) {
        int c = bn + wc * 32 + nf * 16 + (lane & 15);
        #pragma unroll
        for (int r = 0; r < 4; ++r) {
          int t = bm + wr * 32 + mf * 16 + (lane >> 4) * 4 + r;
          float v = acc[mf][nf][r] + bias[c];
          v = v * sigmoidf_(v);                       // silu (fast exp)
          C16[(size_t)t * N + c] = f2bf(v);
        }
      }
  } else {
    // acc -> LDS f32 tile, then row-contiguous packed-bf16 softplus stores
    float* ct = (float*)lds;
    __syncthreads();
    #pragma unroll
    for (int mf = 0; mf < 2; ++mf)
      #pragma unroll
      for (int nf = 0; nf < 2; ++nf) {
        int rbase = wr * 32 + mf * 16 + (lane >> 4) * 4;
        int cc = wc * 32 + nf * 16 + (lane & 15);
        #pragma unroll
        for (int r = 0; r < 4; ++r)
          ct[(rbase + r) * CSTR + cc] = acc[mf][nf][r];
      }
    __syncthreads();
    int w = tid >> 6, l = tid & 63;
    int lcol = (l & 15) * 4;
    #pragma unroll
    for (int p = 0; p < 4; ++p) {
      int lrow = w * 16 + p * 4 + (l >> 4);
      int t = bm + lrow;
      int c = bn + lcol;
      float4 v4 = *(float4*)&ct[lrow * CSTR + lcol];
      float4 bi4 = *(const float4*)(bias + c);
      float u0 = spf_(v4.x + bi4.x);
      float u1 = spf_(v4.y + bi4.y);
      float u2 = spf_(v4.z + bi4.z);
      float u3 = spf_(v4.w + bi4.w);
      *(uint2*)(C16 + (size_t)t * N + c) = packbf4(u0, u1, u2, u3);
    }
  }
}

// ---------------------------------------------------------------------------
// out0 = Hrb + nre * sqrt(bvar * u) * sqrt(0.5)   (pure elementwise, x8)
// ---------------------------------------------------------------------------
__global__ __launch_bounds__(TPB) void fin_k(
    const u16* __restrict__ Hrb, const u16* __restrict__ ub,
    const float* __restrict__ nre, const float* __restrict__ bvar,
    float* __restrict__ out0)
{
  int idx = (blockIdx.x * TPB + threadIdx.x) << 3;    // 8 per thread
  int c = idx & 1023;
  bf8v hb = *(const bf8v*)(Hrb + idx);
  bf8v uv = *(const bf8v*)(ub + idx);
  float4 n0 = *(const float4*)(nre + idx);
  float4 n1 = *(const float4*)(nre + idx + 4);
  float4 b0 = *(const float4*)(bvar + c);
  float4 b1 = *(const float4*)(bvar + c + 4);
  float4 o0, o1;
  const float s2 = 0.7071067811865476f;
  #pragma unroll
  for (int j = 0; j < 4; ++j) {
    float sc = sqrtf(((const float*)&b0)[j] * bf2f((u16)uv[j])) * s2;
    ((float*)&o0)[j] = bf2f((u16)hb[j]) + ((const float*)&n0)[j] * sc;
  }
  #pragma unroll
  for (int j = 0; j < 4; ++j) {
    float sc = sqrtf(((const float*)&b1)[j] * bf2f((u16)uv[4 + j])) * s2;
    ((float*)&o1)[j] = bf2f((u16)hb[4 + j]) + ((const float*)&n1)[j] * sc;
  }
  *(float4*)(out0 + idx)     = o0;
  *(float4*)(out0 + idx + 4) = o1;
}

// ---------------------------------------------------------------------------
extern "C" void kernel_launch(void* const* d_in, const int* in_sizes, int n_in,
                              void* d_out, int out_size, void* d_ws, size_t ws_size,
                              hipStream_t stream) {
  (void)in_sizes; (void)n_in; (void)out_size;

  const float* x_input    = (const float*)d_in[0];
  const float* h_prev_re  = (const float*)d_in[1];
  const float* h_prev_im  = (const float*)d_in[2];
  const float* xg_re      = (const float*)d_in[3];
  const float* xg_im      = (const float*)d_in[4];
  const float* flux_re    = (const float*)d_in[5];
  const float* flux_im    = (const float*)d_in[6];
  const float* dt         = (const float*)d_in[7];
  const float* v_raw_re   = (const float*)d_in[10];
  const float* v_raw_im   = (const float*)d_in[11];
  const float* log_sigma  = (const float*)d_in[12];
  const float* dft_weight = (const float*)d_in[13];
  const float* decay_re   = (const float*)d_in[14];
  const float* decay_im   = (const float*)d_in[15];
  const float* Wi_in      = (const float*)d_in[16];
  const float* bi         = (const float*)d_in[17];
  const float* Wo         = (const float*)d_in[18];
  const float* bo         = (const float*)d_in[19];
  const float* Wg         = (const float*)d_in[20];
  const float* bg         = (const float*)d_in[21];
  const float* ld         = (const float*)d_in[22];
  const float* lf         = (const float*)d_in[23];
  const float* law_re     = (const float*)d_in[24];
  const float* law_im     = (const float*)d_in[25];
  const float* base_noise = (const float*)d_in[26];
  const float* Wu1        = (const float*)d_in[27];
  const float* bu1        = (const float*)d_in[28];
  const float* Wu2        = (const float*)d_in[29];
  const float* bu2        = (const float*)d_in[30];
  const float* noise_re   = (const float*)d_in[31];

  // --- workspace: 16 bf16-sized planes (2MB each) = 32MB --------------------
  const size_t PL16 = 1024ull * 1024ull;        // u16 per plane
  if (ws_size < 16 * PL16 * 2) return;          // too small -> zeros (diagnostic)

  u16* P = (u16*)d_ws;
  u16* Ar  = P + 0 * PL16;   u16* Ai  = P + 1 * PL16;   // A       (dead after A2)
  u16* Nr  = P + 2 * PL16;   u16* Ni  = P + 3 * PL16;   // N = I-A (dead after pair)
  u16* A2r = P + 4 * PL16;   u16* A2i = P + 5 * PL16;   // dead after pair
  u16* A4r = P + 6 * PL16;   u16* A4i = P + 7 * PL16;   // dead after vmt
  u16* T1r = P + 8 * PL16;   u16* T1i = P + 9 * PL16;   // dead after vmt
  // liveness reuse (stream-ordered):
  u16* Mtr  = P + 2 * PL16;             // over Nr/Ni (dead after pair)
  u16* Mti  = P + 3 * PL16;
  u16* Xb   = P + 4 * PL16;             // over A2 (dead after pair... used by vmt? no: vmt reads T1,A4)
  float* PpO = (float*)(P + 0 * PL16);  // 1MB Wo partials (Ar/Ai dead after a2)
  float* PpG = PpO + 262144;            // 0.5MB Wg partials
  float* PpI = (float*)(P + 1 * PL16);  // 1MB Wi partials (Ai plane; dead after a2)
  u16* ub   = P + 6 * PL16;             // over A4 (dead after vmt)
  u16* Hrb  = P + 10 * PL16;            // 8MB, P10..P13
  u16* mlp1b = P + 14 * PL16;           // 4096x256
  u16* Wu1b  = P + 15 * PL16;           // 262144 u16
  u16* Wu2b  = Wu1b + 262144;
  float* sm  = (float*)(P + 15 * PL16 + 524288);
  float* xin  = sm;                     // 16x2048
  float* proj = xin + 32768;            // 16x2048
  float* FNr  = proj + 32768;           // 16x1024
  float* FNi  = FNr + 16384;
  float* gate = FNi + 16384;            // 16x1024
  float* od_re = gate + 16384;
  float* od_im = od_re + 1024;
  float* of_re = od_im + 1024;
  float* of_im = of_re + 1024;
  float* bvar  = of_im + 1024;

  float* out0f = (float*)d_out;                       // 4096x1024 f32 (real)
  float* out1f = out0f + (size_t)4096 * 1024;         // 16x1024 f32 (real)

  // --- Cayley: V = 2*(I-A)(I+A^2)(I+A^4) - I, fused Mt build ----------------
  build_a_k<<<4096, TPB, 0, stream>>>(v_raw_re, v_raw_im, Ar, Ai, Nr, Ni);
  cgemm_a2_k<<<256, TPB, 0, stream>>>(Ar, Ai, A2r, A2i);                 // A2 = A@A
  cgemm_pair_k<<<512, TPB, 0, stream>>>(A2r, A2i, Nr, Ni,                // A4 = A2@A2
                                        A4r, A4i, T1r, T1i);             // T1 = N@A2+N
  cgemm_vmt_k<<<256, TPB, 0, stream>>>(T1r, T1i, A4r, A4i,
                                       log_sigma, dft_weight, Mtr, Mti); // Mt direct
  conv_all_k<<<2308, TPB, 0, stream>>>(x_input, Wu1, Wu2,
                                       ld, lf, law_re, law_im, dt, base_noise,
                                       Xb, Wu1b, Wu2b,
                                       od_re, od_im, of_re, of_im, bvar);

  // --- B=16 chain: split-K MFMA gemms ---------------------------------------
  sgemm16_k<<<dim3(32, 8), TPB, 0, stream>>>(xg_re, xg_im, Wi_in, PpI, 2048);
  red16_k<<<128, TPB, 0, stream>>>(PpI, bi, xin, 2048, 0);
  flux_k<<<64, TPB, 0, stream>>>(xin, flux_re, flux_im, decay_re, decay_im,
                                 FNr, FNi, out1f);
  sgemm16_wog_k<<<dim3(48, 8), TPB, 0, stream>>>(FNr, FNi, Wo, Wg, PpO, PpG);
  red16_wog_k<<<192, TPB, 0, stream>>>(PpO, PpG, bo, bg, proj, gate);

  // --- x_tilde = Xb@M fused with h_next epilogue -> Hrb bf16 (128x64 tile) --
  xmh_nt_k<<<512, TPB, 0, stream>>>(Xb, Mtr, Mti, gate, proj,
                                    od_re, od_im, of_re, of_im,
                                    h_prev_re, h_prev_im, Hrb);

  // --- u-MLP (MFMA) + elementwise final -------------------------------------
  rgemm_nt_k<32, 0><<<256, TPB, 0, stream>>>(Hrb, Wu1b, bu1, mlp1b, 2, 256);
  rgemm_nt_k<8, 2><<<1024, TPB, 0, stream>>>(mlp1b, Wu2b, bu2, ub, 4, 1024);
  fin_k<<<2048, TPB, 0, stream>>>(Hrb, ub, noise_re, bvar, out0f);
}